// Round 7
// baseline (873.729 us; speedup 1.0000x reference)
//
#include <hip/hip_runtime.h>
#include <hip/hip_bf16.h>
#include <stdint.h>

// AttentiveFP readout, MEGA-KERNEL: B=2048 graphs x (48+1 virtual) x D=256, H=8, 4 steps.
// The whole recurrence is per-graph independent -> one kernel runs all 4 steps.
// 256 blocks x 512 threads (8 waves); wave w owns graph blockIdx*8+w.
//  - A (48x256 bf16) in registers (af[8][3]); x' round-trips a wave-private 24KB global
//    scratch (L2-hot: written by the same wave that reloads it next step).
//  - h GEMM: 8 strips of 64 cols; B (=[Wg;Ws]^T fragment-major BP) staged 32KB/strip via
//    global_load_lds, double-buffered; all 8 waves consume each strip (768 MFMA/stage).
//  - Attention strip-local, fully in-register (strip = 2 heads), shfl butterflies.
//  - GRU gates: ONE block-level MFMA tile A=[8 g0 rows; 8 state rows] (100% util) x
//    N=1536 ([wx|wh] fragment-major GP), direct L2 B loads; outputs via LDS; GRU f32.
//  - hv/sv for next step: post-GRU state @ [Wg;Ws] (GP cols 1536..2047).
//  - Final: state @ proj_w + proj_b (GP cols 2048..2303) -> out. Total 2 launches.

#define NEG_SLOPE 0.2f

typedef unsigned short u16;
typedef short s16x8 __attribute__((ext_vector_type(8)));
typedef float f32x4 __attribute__((ext_vector_type(4)));
typedef u16 u16x8 __attribute__((ext_vector_type(8)));

__device__ __forceinline__ u16 f2bf(float f) {
  union { float f; uint32_t u; } v; v.f = f;
  uint32_t r = (v.u + 0x7FFFu + ((v.u >> 16) & 1u)) >> 16;  // RNE
  return (u16)r;
}
__device__ __forceinline__ float bf2f(u16 h) {
  union { uint32_t u; float f; } v; v.u = ((uint32_t)h) << 16;
  return v.f;
}
__device__ __forceinline__ s16x8 pack8(f32x4 a, f32x4 b) {
  s16x8 r;
  r[0] = (short)f2bf(a[0]); r[1] = (short)f2bf(a[1]);
  r[2] = (short)f2bf(a[2]); r[3] = (short)f2bf(a[3]);
  r[4] = (short)f2bf(b[0]); r[5] = (short)f2bf(b[1]);
  r[6] = (short)f2bf(b[2]); r[7] = (short)f2bf(b[3]);
  return r;
}

__device__ __forceinline__ void gload_lds16(const void* g, void* l) {
  __builtin_amdgcn_global_load_lds(
      (const __attribute__((address_space(1))) void*)g,
      (__attribute__((address_space(3))) void*)l, 16, 0, 0);
}

__device__ __forceinline__ float redsum_lr(float v) {
  v += __shfl_xor(v, 1); v += __shfl_xor(v, 2);
  v += __shfl_xor(v, 4); v += __shfl_xor(v, 8);
  return v;
}
__device__ __forceinline__ float redsum_lk(float v) {
  v += __shfl_xor(v, 16); v += __shfl_xor(v, 32);
  return v;
}
__device__ __forceinline__ float redmax_lk(float v) {
  v = fmaxf(v, __shfl_xor(v, 16)); v = fmaxf(v, __shfl_xor(v, 32));
  return v;
}

// ---------------------------------------------------------------------------
// MEGA kernel
// ---------------------------------------------------------------------------
__global__ __launch_bounds__(512, 2)
void mega_kernel(const float* __restrict__ nf, const u16* __restrict__ BP,
                 const u16* __restrict__ GP, const float* __restrict__ asrc,
                 const float* __restrict__ adst, const float* __restrict__ bx,
                 const float* __restrict__ bh, const float* __restrict__ pb,
                 u16* __restrict__ XR, float* __restrict__ out) {
  __shared__ __align__(16) u16 ldsB[2][16384];   // 64KB strip dbuf (aliased as gout)
  __shared__ __align__(16) float hvsv[8][512];   // 16KB: [hv | sv] per graph
  __shared__ float stF[8][256];                  // 8KB f32 state
  __shared__ __align__(16) u16 stH[8][264];      // bf16 state (padded)
  __shared__ __align__(16) u16 g0L[8][264];      // bf16 g0 (padded)
  float* gout = (float*)&ldsB[0][0];             // gates outputs (48KB), aliases dbuf
  const int tid = threadIdx.x, w = tid >> 6, l = tid & 63, lr = l & 15, lk = l >> 4;
  const size_t g = (size_t)blockIdx.x * 8 + w;

#define STAGE(S, BUF)                                                          \
  {                                                                            \
    _Pragma("unroll") for (int i_ = 0; i_ < 4; ++i_)                           \
        gload_lds16(BP + ((size_t)(S)*2048 + i_ * 512 + tid) * 8,              \
                    &ldsB[BUF][(i_ * 512 + w * 64) * 8]);                      \
  }

  // ---- init: af from nf (f32), state0 = column sums ----
  s16x8 af[8][3];
#pragma unroll
  for (int kc = 0; kc < 8; ++kc) {
    float ss[8] = {0.f, 0.f, 0.f, 0.f, 0.f, 0.f, 0.f, 0.f};
#pragma unroll
    for (int mi = 0; mi < 3; ++mi) {
      const float* src = nf + ((size_t)g * 48 + mi * 16 + lr) * 256 + kc * 32 + lk * 8;
      f32x4 u0 = *(const f32x4*)src, u1 = *(const f32x4*)(src + 4);
#pragma unroll
      for (int e = 0; e < 4; ++e) { ss[e] += u0[e]; ss[4 + e] += u1[e]; }
      af[kc][mi] = pack8(u0, u1);
    }
#pragma unroll
    for (int e = 0; e < 8; ++e) ss[e] = redsum_lr(ss[e]);
    if (lr == 0) {
#pragma unroll
      for (int e = 0; e < 8; ++e) {
        stF[w][kc * 32 + lk * 8 + e] = ss[e];
        stH[w][kc * 32 + lk * 8 + e] = f2bf(ss[e]);
      }
    }
  }
  asm volatile("s_waitcnt lgkmcnt(0)" ::: "memory");
  __builtin_amdgcn_s_barrier();
  STAGE(0, 0)

  // HV phase: hvsv = state @ [Wg;Ws]  (A rows = stH dup, N=512 via GP n16 96..127)
#define HV_PHASE()                                                             \
  {                                                                            \
    s16x8 ah[8];                                                               \
    _Pragma("unroll") for (int kc = 0; kc < 8; ++kc)                           \
        ah[kc] = *(const s16x8*)&stH[lr & 7][kc * 32 + lk * 8];                \
    _Pragma("unroll") for (int i = 0; i < 4; ++i) {                            \
      const int n16 = 96 + w * 4 + i;                                          \
      f32x4 a = (f32x4){0.f, 0.f, 0.f, 0.f};                                   \
      _Pragma("unroll") for (int kc = 0; kc < 8; ++kc) {                       \
        s16x8 bfr = *(const s16x8*)(GP + ((size_t)(n16 * 8 + kc) * 64 + l) * 8); \
        a = __builtin_amdgcn_mfma_f32_16x16x32_bf16(ah[kc], bfr, a, 0, 0, 0);  \
      }                                                                        \
      const int col = (n16 - 96) * 16 + lr;                                    \
      if (lk < 2) {                                                            \
        _Pragma("unroll") for (int j = 0; j < 4; ++j)                          \
            hvsv[lk * 4 + j][col] = a[j];                                      \
      }                                                                        \
    }                                                                          \
  }

  HV_PHASE()
  asm volatile("s_waitcnt lgkmcnt(0)" ::: "memory");
  __builtin_amdgcn_s_barrier();

  for (int t = 0; t < 4; ++t) {
    const int NS = (t < 3) ? 8 : 4;  // last step: Wg strips only

    // e_dst per head from hv
    float ed[8];
#pragma unroll
    for (int g4 = 0; g4 < 4; ++g4) {
      float p = hvsv[w][g4 * 64 + l] * adst[g4 * 64 + l];
      p += __shfl_xor(p, 1); p += __shfl_xor(p, 2); p += __shfl_xor(p, 4);
      p += __shfl_xor(p, 8); p += __shfl_xor(p, 16);
      ed[2 * g4] = __shfl(p, 0);
      ed[2 * g4 + 1] = __shfl(p, 32);
    }

    // ---- strips: h GEMM + attention (s<4) / x' (s>=4) ----
#pragma unroll
    for (int s = 0; s < 8; ++s) {
      if (s < NS) {
        asm volatile("s_waitcnt vmcnt(0) lgkmcnt(0)" ::: "memory");
        __builtin_amdgcn_s_barrier();
        if (s + 1 < NS) STAGE(s + 1, (s + 1) & 1)

        f32x4 acc[3][4];
#pragma unroll
        for (int mi = 0; mi < 3; ++mi)
#pragma unroll
          for (int ni = 0; ni < 4; ++ni) acc[mi][ni] = (f32x4){0.f, 0.f, 0.f, 0.f};
        const u16* bufB = ldsB[s & 1];
#pragma unroll
        for (int kc = 0; kc < 8; ++kc) {
          s16x8 bfr[4];
#pragma unroll
          for (int ni = 0; ni < 4; ++ni)
            bfr[ni] = *(const s16x8*)&bufB[((kc * 4 + ni) * 64 + l) * 8];
#pragma unroll
          for (int mi = 0; mi < 3; ++mi)
#pragma unroll
            for (int ni = 0; ni < 4; ++ni)
              acc[mi][ni] = __builtin_amdgcn_mfma_f32_16x16x32_bf16(
                  af[kc][mi], bfr[ni], acc[mi][ni], 0, 0, 0);
        }

        if (s < 4) {
          // strip-local attention: heads 2s, 2s+1
          float sv0[4];
#pragma unroll
          for (int ni = 0; ni < 4; ++ni)
            sv0[ni] = hvsv[w][256 + s * 64 + ni * 16 + lr];
#pragma unroll
          for (int hi = 0; hi < 2; ++hi) {
            const int nb = 2 * hi;
            const float as0 = asrc[(2 * s + hi) * 32 + lr];
            const float as1 = asrc[(2 * s + hi) * 32 + 16 + lr];
            float al[3][4];
            float m = -1e30f;
#pragma unroll
            for (int mi = 0; mi < 3; ++mi)
#pragma unroll
              for (int j = 0; j < 4; ++j) {
                float p = acc[mi][nb][j] * as0 + acc[mi][nb + 1][j] * as1;
                p = redsum_lr(p) + ed[2 * s + hi];
                p = (p > 0.f) ? p : NEG_SLOPE * p;
                al[mi][j] = p;
                m = fmaxf(m, p);
              }
            m = redmax_lk(m);
            float sm = 0.f;
#pragma unroll
            for (int mi = 0; mi < 3; ++mi)
#pragma unroll
              for (int j = 0; j < 4; ++j) {
                float ex = expf(al[mi][j] - m);
                al[mi][j] = ex; sm += ex;
              }
            sm = redsum_lk(sm);
            const float inv = 1.f / sm;
#pragma unroll
            for (int ni = nb; ni <= nb + 1; ++ni) {
              float mm = 0.f;
#pragma unroll
              for (int mi = 0; mi < 3; ++mi)
#pragma unroll
                for (int j = 0; j < 4; ++j) mm += al[mi][j] * acc[mi][ni][j];
              mm = redsum_lk(mm) * inv;
              if (lk == 0)
                g0L[w][s * 64 + ni * 16 + lr] = f2bf(fmaxf(mm + sv0[ni], 0.f));
            }
          }
        } else {
          // x' = relu -> XR (wave-private, L2-hot round trip)
#pragma unroll
          for (int mi = 0; mi < 3; ++mi)
#pragma unroll
            for (int ni = 0; ni < 4; ++ni)
#pragma unroll
              for (int j = 0; j < 4; ++j)
                XR[((size_t)g * 48 + mi * 16 + lk * 4 + j) * 256 + (s - 4) * 64 +
                   ni * 16 + lr] = f2bf(fmaxf(acc[mi][ni][j], 0.f));
        }
      }
    }

    // ---- gates GEMM: A=[8 g0 rows; 8 state rows], N=1536 ([wx|wh]) ----
    asm volatile("s_waitcnt vmcnt(0) lgkmcnt(0)" ::: "memory");  // drains XR stores too
    __builtin_amdgcn_s_barrier();
    {
      s16x8 ag[8];
#pragma unroll
      for (int kc = 0; kc < 8; ++kc)
        ag[kc] = (lr < 8) ? *(const s16x8*)&g0L[lr][kc * 32 + lk * 8]
                          : *(const s16x8*)&stH[lr - 8][kc * 32 + lk * 8];
#pragma unroll
      for (int i = 0; i < 12; ++i) {
        const int n16 = w * 12 + i;
        f32x4 a = (f32x4){0.f, 0.f, 0.f, 0.f};
#pragma unroll
        for (int kc = 0; kc < 8; ++kc) {
          s16x8 bfr = *(const s16x8*)(GP + ((size_t)(n16 * 8 + kc) * 64 + l) * 8);
          a = __builtin_amdgcn_mfma_f32_16x16x32_bf16(ag[kc], bfr, a, 0, 0, 0);
        }
        const int col = n16 * 16 + lr;
#pragma unroll
        for (int j = 0; j < 4; ++j) {
          const int row = lk * 4 + j;
          if (n16 < 48) { if (row < 8) gout[row * 768 + col] = a[j]; }
          else          { if (row >= 8) gout[6144 + (row - 8) * 768 + (col - 768)] = a[j]; }
        }
      }
    }
    asm volatile("s_waitcnt lgkmcnt(0)" ::: "memory");
    __builtin_amdgcn_s_barrier();

    // ---- GRU (f32): thread handles 4 dims of its wave's graph ----
    {
#pragma unroll
      for (int jj = 0; jj < 4; ++jj) {
        const int d = l * 4 + jj;
        float xz = gout[w * 768 + d] + bx[d];
        float xr_ = gout[w * 768 + 256 + d] + bx[256 + d];
        float xh = gout[w * 768 + 512 + d] + bx[512 + d];
        float hz = gout[6144 + w * 768 + d] + bh[d];
        float hr = gout[6144 + w * 768 + 256 + d] + bh[256 + d];
        float hh = gout[6144 + w * 768 + 512 + d] + bh[512 + d];
        float z = 1.f / (1.f + expf(-(xz + hz)));
        float r = 1.f / (1.f + expf(-(xr_ + hr)));
        float n = tanhf(xh + r * hh);
        float h0 = stF[w][d];
        float sn = z * h0 + (1.f - z) * n;
        stF[w][d] = sn;
        stH[w][d] = f2bf(sn);
      }
    }
    asm volatile("s_waitcnt lgkmcnt(0)" ::: "memory");
    __builtin_amdgcn_s_barrier();

    if (t < 3) {
      STAGE(0, 0)   // next step's first strip (dbuf free: gates reads done)
      HV_PHASE()    // hv/sv from post-GRU state
      // reload af from XR (written by this wave above)
#pragma unroll
      for (int kc = 0; kc < 8; ++kc)
#pragma unroll
        for (int mi = 0; mi < 3; ++mi)
          af[kc][mi] = *(const s16x8*)(XR + ((size_t)g * 48 + mi * 16 + lr) * 256 +
                                       kc * 32 + lk * 8);
      asm volatile("s_waitcnt lgkmcnt(0)" ::: "memory");
      __builtin_amdgcn_s_barrier();  // hvsv visible before next-iter e_dst
    } else {
      // ---- projection: out = state @ pw + pb  (GP n16 128..143) ----
      s16x8 ah[8];
#pragma unroll
      for (int kc = 0; kc < 8; ++kc)
        ah[kc] = *(const s16x8*)&stH[lr & 7][kc * 32 + lk * 8];
#pragma unroll
      for (int i = 0; i < 2; ++i) {
        const int n16 = 128 + w * 2 + i;
        f32x4 a = (f32x4){0.f, 0.f, 0.f, 0.f};
#pragma unroll
        for (int kc = 0; kc < 8; ++kc) {
          s16x8 bfr = *(const s16x8*)(GP + ((size_t)(n16 * 8 + kc) * 64 + l) * 8);
          a = __builtin_amdgcn_mfma_f32_16x16x32_bf16(ah[kc], bfr, a, 0, 0, 0);
        }
        const int col = (n16 - 128) * 16 + lr;
        if (lk < 2) {
#pragma unroll
          for (int j = 0; j < 4; ++j)
            out[((size_t)blockIdx.x * 8 + lk * 4 + j) * 256 + col] = a[j] + pb[col];
        }
      }
    }
  }
#undef STAGE
#undef HV_PHASE
}

// ---------------------------------------------------------------------------
// Weight packing: BP = [Wg|Ws] fragment-major (16384 chunks of 16B);
// GP = [wx | wh | Wg | Ws | pw] fragment-major, N=2304 (73728 chunks).
// chunk formulas match the kernel's bfr reads: elem e of chunk ((n16*8+kc)*64+l)
// = W[kc*32+(l>>4)*8+e][n16*16+(l&15)].
// ---------------------------------------------------------------------------
__global__ void pack_w(const float* __restrict__ Wg, const float* __restrict__ Ws,
                       const float* __restrict__ wx, const float* __restrict__ wh,
                       const float* __restrict__ pw,
                       u16* __restrict__ BP, u16* __restrict__ GP) {
  int c = blockIdx.x * 256 + threadIdx.x;
  if (c < 16384) {
    int l = c & 63, ni = (c >> 6) & 3, kc = (c >> 8) & 7, s = c >> 11;
    int n = s * 64 + ni * 16 + (l & 15);
    int k0 = kc * 32 + (l >> 4) * 8;
    const float* W = (n < 256) ? Wg : Ws;
    int nn = n & 255;
    u16x8 o;
#pragma unroll
    for (int e = 0; e < 8; ++e) o[e] = f2bf(W[(size_t)(k0 + e) * 256 + nn]);
    *(u16x8*)(BP + (size_t)c * 8) = o;
  } else if (c < 16384 + 73728) {
    int cc = c - 16384;
    int l = cc & 63, kc = (cc >> 6) & 7, n16 = cc >> 9;
    int n = n16 * 16 + (l & 15);
    int k0 = kc * 32 + (l >> 4) * 8;
    const float* W; int col, str;
    if (n < 768)       { W = wx; col = n;        str = 768; }
    else if (n < 1536) { W = wh; col = n - 768;  str = 768; }
    else if (n < 1792) { W = Wg; col = n - 1536; str = 256; }
    else if (n < 2048) { W = Ws; col = n - 1792; str = 256; }
    else               { W = pw; col = n - 2048; str = 256; }
    u16x8 o;
#pragma unroll
    for (int e = 0; e < 8; ++e) o[e] = f2bf(W[(size_t)(k0 + e) * str + col]);
    *(u16x8*)(GP + (size_t)cc * 8) = o;
  }
}

extern "C" void kernel_launch(void* const* d_in, const int* in_sizes, int n_in,
                              void* d_out, int out_size, void* d_ws, size_t ws_size,
                              hipStream_t stream) {
  const float* nf  = (const float*)d_in[0];
  const float* Wg  = (const float*)d_in[2];
  const float* Ws  = (const float*)d_in[3];
  const float* asr = (const float*)d_in[4];
  const float* ads = (const float*)d_in[5];
  const float* wx  = (const float*)d_in[6];
  const float* wh  = (const float*)d_in[7];
  const float* bx  = (const float*)d_in[8];
  const float* bh  = (const float*)d_in[9];
  const float* pw  = (const float*)d_in[10];
  const float* pb  = (const float*)d_in[11];
  float* out = (float*)d_out;

  char* p = (char*)d_ws;
  size_t off = 0;
  auto alloc = [&](size_t bytes) { char* r = p + off; off += (bytes + 255) & ~255ULL; return r; };
  u16* BP = (u16*)alloc((size_t)512 * 256 * 2);    // [Wg|Ws] strips for h GEMM
  u16* GP = (u16*)alloc((size_t)2304 * 256 * 2);   // [wx|wh|Wg|Ws|pw] for gates/HV/proj
  u16* XR = (u16*)alloc((size_t)98304 * 256 * 2);  // x' scratch (bf16, wave-private)

  pack_w<<<352, 256, 0, stream>>>(Wg, Ws, wx, wh, pw, BP, GP);
  mega_kernel<<<256, 512, 0, stream>>>(nf, BP, GP, asr, ads, bx, bh, pb, XR, out);
}

// Round 8
// 291.606 us; speedup vs baseline: 2.9963x; 2.9963x over previous
//
#include <hip/hip_runtime.h>
#include <hip/hip_bf16.h>
#include <stdint.h>

// AttentiveFP readout: B=2048 graphs x (48 real + 1 virtual) nodes, D=256, H=8, DH=32, 4 steps.
// Round-8 structure (round-6 base + folds):
//  - fused_step: 4 graphs/block (wave=graph), A in registers, B ([Wg|Ws] fragment-major)
//    staged in 16 strips of 16KB (32 cols), double-buffered global_load_lds; strip s<8 =
//    head-s attention fully in-register; s>=8 = relu->Xn. 2 blocks/CU.
//  - e_dst folded: ED[b][h] = state . WGAD[:,h], WGAD = Wg @ adst[h] (precomputed once);
//    computed inside prep/gru where state is live.
//  - sv via small GEMM SV = state @ Ws (N=256; was N=512 HVSV).
//  - gates GEMM + GRU elementwise per step; final projection GEMM.

#define NEG_SLOPE 0.2f

typedef unsigned short u16;
typedef short s16x8 __attribute__((ext_vector_type(8)));
typedef float f32x4 __attribute__((ext_vector_type(4)));
typedef u16 u16x4 __attribute__((ext_vector_type(4)));
typedef u16 u16x8 __attribute__((ext_vector_type(8)));

__device__ __forceinline__ u16 f2bf(float f) {
  union { float f; uint32_t u; } v; v.f = f;
  uint32_t r = (v.u + 0x7FFFu + ((v.u >> 16) & 1u)) >> 16;  // RNE
  return (u16)r;
}
__device__ __forceinline__ float bf2f(u16 h) {
  union { uint32_t u; float f; } v; v.u = ((uint32_t)h) << 16;
  return v.f;
}

__device__ __forceinline__ void gload_lds16(const void* g, void* l) {
  __builtin_amdgcn_global_load_lds(
      (const __attribute__((address_space(1))) void*)g,
      (__attribute__((address_space(3))) void*)l, 16, 0, 0);
}

__device__ __forceinline__ float redsum_lr(float v) {
  v += __shfl_xor(v, 1); v += __shfl_xor(v, 2);
  v += __shfl_xor(v, 4); v += __shfl_xor(v, 8);
  return v;
}
__device__ __forceinline__ float redsum_lk(float v) {
  v += __shfl_xor(v, 16); v += __shfl_xor(v, 32);
  return v;
}
__device__ __forceinline__ float redmax_lk(float v) {
  v = fmaxf(v, __shfl_xor(v, 16)); v = fmaxf(v, __shfl_xor(v, 32));
  return v;
}
__device__ __forceinline__ float redsum_wave(float v) {
  v += __shfl_xor(v, 1); v += __shfl_xor(v, 2); v += __shfl_xor(v, 4);
  v += __shfl_xor(v, 8); v += __shfl_xor(v, 16); v += __shfl_xor(v, 32);
  return v;
}

// ---------------------------------------------------------------------------
// FUSED step: 512 blocks x 256 threads; wave w handles graph blockIdx*4+w.
// 16 strips of 32 cols; strip s<8 = attention head s (Wg cols), s>=8 = Xn (Ws cols).
// ---------------------------------------------------------------------------
__global__ __launch_bounds__(256, 2)
void fused_step(const u16* __restrict__ X, const u16* __restrict__ BP,
                const float* __restrict__ SV, const float* __restrict__ ED,
                const float* __restrict__ asrc, u16* __restrict__ GS,
                u16* __restrict__ Xn) {
  __shared__ u16 ldsB[2][8192];  // 2 x 16KB strip buffers (fragment-major)
  const int tid = threadIdx.x;
  const int w = tid >> 6, l = tid & 63, lr = l & 15, lk = l >> 4;
  const int b = blockIdx.x * 4 + w;
  const u16* Xg = X + (size_t)b * 48 * 256;

#define STAGE(S, BUF)                                                          \
  {                                                                            \
    _Pragma("unroll") for (int i_ = 0; i_ < 4; ++i_)                           \
        gload_lds16(BP + ((size_t)(S)*1024 + i_ * 256 + tid) * 8,              \
                    &ldsB[BUF][(i_ * 256 + w * 64) * 8]);                      \
  }

  const int NS = Xn ? 16 : 8;  // last step: attention strips only
  STAGE(0, 0)

  // ---- prologue preloads (overlap the stage-0 latency) ----
  s16x8 af[8][3];
#pragma unroll
  for (int kc = 0; kc < 8; ++kc)
#pragma unroll
    for (int mi = 0; mi < 3; ++mi)
      af[kc][mi] = *(const s16x8*)(Xg + (size_t)(mi * 16 + lr) * 256 + kc * 32 + lk * 8);

  float ed8[8], asA[8], asB[8], svA[8][2];
#pragma unroll
  for (int h = 0; h < 8; ++h) {
    ed8[h] = ED[(size_t)b * 8 + h];
    asA[h] = asrc[h * 32 + lr];
    asB[h] = asrc[h * 32 + 16 + lr];
#pragma unroll
    for (int ni = 0; ni < 2; ++ni)
      svA[h][ni] = SV[(size_t)b * 256 + h * 32 + ni * 16 + lr];
  }

#pragma unroll
  for (int s = 0; s < 16; ++s) {
    if (s < NS) {
      asm volatile("s_waitcnt vmcnt(0) lgkmcnt(0)" ::: "memory");
      __builtin_amdgcn_s_barrier();
      if (s + 1 < NS) STAGE(s + 1, (s + 1) & 1)

      f32x4 acc[3][2];
#pragma unroll
      for (int mi = 0; mi < 3; ++mi)
#pragma unroll
        for (int ni = 0; ni < 2; ++ni) acc[mi][ni] = (f32x4){0.f, 0.f, 0.f, 0.f};

      const u16* bufB = ldsB[s & 1];
#pragma unroll
      for (int kc = 0; kc < 8; ++kc) {
        s16x8 bfr[2];
#pragma unroll
        for (int ni = 0; ni < 2; ++ni)
          bfr[ni] = *(const s16x8*)&bufB[((kc * 2 + ni) * 64 + l) * 8];
#pragma unroll
        for (int mi = 0; mi < 3; ++mi)
#pragma unroll
          for (int ni = 0; ni < 2; ++ni)
            acc[mi][ni] = __builtin_amdgcn_mfma_f32_16x16x32_bf16(
                af[kc][mi], bfr[ni], acc[mi][ni], 0, 0, 0);
      }

      if (s < 8) {
        // ---- attention for head s (strip cols = head s's 32 dims) ----
        float al[3][4];
        float m = -1e30f;
#pragma unroll
        for (int mi = 0; mi < 3; ++mi)
#pragma unroll
          for (int j = 0; j < 4; ++j) {
            float p = acc[mi][0][j] * asA[s] + acc[mi][1][j] * asB[s];
            p = redsum_lr(p) + ed8[s];           // e = e_src + e_dst
            p = (p > 0.f) ? p : NEG_SLOPE * p;   // leaky_relu
            al[mi][j] = p;
            m = fmaxf(m, p);
          }
        m = redmax_lk(m);  // max over all 48 nodes
        float sm = 0.f;
#pragma unroll
        for (int mi = 0; mi < 3; ++mi)
#pragma unroll
          for (int j = 0; j < 4; ++j) {
            float ex = expf(al[mi][j] - m);
            al[mi][j] = ex; sm += ex;
          }
        sm = redsum_lk(sm);
        const float inv = 1.f / sm;
#pragma unroll
        for (int ni = 0; ni < 2; ++ni) {
          float mm = 0.f;
#pragma unroll
          for (int mi = 0; mi < 3; ++mi)
#pragma unroll
            for (int j = 0; j < 4; ++j) mm += al[mi][j] * acc[mi][ni][j];
          mm = redsum_lk(mm) * inv;  // msg over 48 nodes
          if (lk == 0)
            GS[(size_t)b * 512 + s * 32 + ni * 16 + lr] =
                f2bf(fmaxf(mm + svA[s][ni], 0.f));  // g0 = relu(msg + sv)
        }
      } else {
        // ---- Ws strip: relu -> Xn ----
#pragma unroll
        for (int mi = 0; mi < 3; ++mi)
#pragma unroll
          for (int ni = 0; ni < 2; ++ni)
#pragma unroll
            for (int j = 0; j < 4; ++j)
              Xn[(size_t)(b * 48 + mi * 16 + lk * 4 + j) * 256 + (s - 8) * 32 +
                 ni * 16 + lr] = f2bf(fmaxf(acc[mi][ni][j], 0.f));
      }
    }
  }
#undef STAGE
}

// ---------------------------------------------------------------------------
// Generic bf16 GEMM: C[M,N] = A[M,K=256] * Bt[N,K=256]^T, 128x128, pipelined.
// EPI: 0 = f32 store; 2 = f32 + bias (projection).
// ---------------------------------------------------------------------------
template<int EPI>
__global__ __launch_bounds__(256)
void gemm_bt(const u16* __restrict__ A, int lda,
             const u16* __restrict__ Bt,
             float* __restrict__ Cf, int ldc, const float* __restrict__ bias) {
  __shared__ u16 ldsA[2][2 * 128 * 32];
  __shared__ u16 ldsB[2][2 * 128 * 32];
  const int tid = threadIdx.x;
  const int w = tid >> 6, l = tid & 63;
  const int wr = w >> 1, wc = w & 1;
  const int lr = l & 15, lk = l >> 4;
  const int sxor = (lr >> 1) & 3;
  const int m0 = blockIdx.x * 128, n0 = blockIdx.y * 128;

#define STAGE_AB(KT, BUF)                                                      \
  {                                                                            \
    const u16* Ag = A + (size_t)m0 * lda + (KT)*64;                            \
    const u16* Bg = Bt + (size_t)n0 * 256 + (KT)*64;                           \
    _Pragma("unroll") for (int i = 0; i < 4; ++i) {                            \
      int q = i * 256 + tid;                                                   \
      int h2 = q >> 9, r = (q >> 2) & 127, c4 = q & 3;                         \
      int c4s = c4 ^ ((r >> 1) & 3);                                           \
      gload_lds16(Ag + (size_t)r * lda + h2 * 32 + c4s * 8,                    \
                  &ldsA[BUF][(i * 256 + w * 64) * 8]);                         \
      gload_lds16(Bg + (size_t)r * 256 + h2 * 32 + c4s * 8,                    \
                  &ldsB[BUF][(i * 256 + w * 64) * 8]);                         \
    }                                                                          \
  }

  f32x4 acc[4][4];
#pragma unroll
  for (int i = 0; i < 4; ++i)
#pragma unroll
    for (int j = 0; j < 4; ++j) acc[i][j] = (f32x4){0.f, 0.f, 0.f, 0.f};

  STAGE_AB(0, 0)
#pragma unroll
  for (int kt = 0; kt < 4; ++kt) {
    __syncthreads();
    if (kt < 3) STAGE_AB(kt + 1, (kt + 1) & 1)
    const u16* bA = ldsA[kt & 1];
    const u16* bB = ldsB[kt & 1];
#pragma unroll
    for (int hh = 0; hh < 2; ++hh) {
      s16x8 af[4], bfr[4];
#pragma unroll
      for (int mi = 0; mi < 4; ++mi)
        af[mi] = *(const s16x8*)&bA[(hh * 128 + wr * 64 + mi * 16 + lr) * 32 +
                                    (lk ^ sxor) * 8];
#pragma unroll
      for (int ni = 0; ni < 4; ++ni)
        bfr[ni] = *(const s16x8*)&bB[(hh * 128 + wc * 64 + ni * 16 + lr) * 32 +
                                     (lk ^ sxor) * 8];
#pragma unroll
      for (int mi = 0; mi < 4; ++mi)
#pragma unroll
        for (int ni = 0; ni < 4; ++ni)
          acc[mi][ni] = __builtin_amdgcn_mfma_f32_16x16x32_bf16(af[mi], bfr[ni],
                                                                acc[mi][ni], 0, 0, 0);
    }
  }
#undef STAGE_AB

#pragma unroll
  for (int mi = 0; mi < 4; ++mi) {
#pragma unroll
    for (int ni = 0; ni < 4; ++ni) {
      f32x4 v = acc[mi][ni];
      int r = m0 + wr * 64 + mi * 16 + lk * 4;
      int c = n0 + wc * 64 + ni * 16 + lr;
#pragma unroll
      for (int j = 0; j < 4; ++j) {
        float fv = v[j];
        if (EPI == 0) Cf[(size_t)(r + j) * ldc + c] = fv;
        else          Cf[(size_t)(r + j) * ldc + c] = fv + bias[c];
      }
    }
  }
}

// Merged GRU-gate GEMM: blockIdx.y<6 -> G1 = g0@wx ; else G2 = state@wh. Pipelined.
__global__ __launch_bounds__(256)
void gemm_gates(const u16* __restrict__ GS, const u16* __restrict__ WXT,
                const u16* __restrict__ WHT, float* __restrict__ G1,
                float* __restrict__ G2) {
  __shared__ u16 ldsA[2][2 * 128 * 32];
  __shared__ u16 ldsB[2][2 * 128 * 32];
  const bool second = blockIdx.y >= 6;
  const u16* A = GS + (second ? 256 : 0);
  const u16* Bt = second ? WHT : WXT;
  float* Cf = second ? G2 : G1;
  const int n0 = (second ? blockIdx.y - 6 : blockIdx.y) * 128;
  const int m0 = blockIdx.x * 128;
  const int tid = threadIdx.x;
  const int w = tid >> 6, l = tid & 63;
  const int wr = w >> 1, wc = w & 1;
  const int lr = l & 15, lk = l >> 4;
  const int sxor = (lr >> 1) & 3;

#define STAGE_AB(KT, BUF)                                                      \
  {                                                                            \
    const u16* Ag = A + (size_t)m0 * 512 + (KT)*64;                            \
    const u16* Bg = Bt + (size_t)n0 * 256 + (KT)*64;                           \
    _Pragma("unroll") for (int i = 0; i < 4; ++i) {                            \
      int q = i * 256 + tid;                                                   \
      int h2 = q >> 9, r = (q >> 2) & 127, c4 = q & 3;                         \
      int c4s = c4 ^ ((r >> 1) & 3);                                           \
      gload_lds16(Ag + (size_t)r * 512 + h2 * 32 + c4s * 8,                    \
                  &ldsA[BUF][(i * 256 + w * 64) * 8]);                         \
      gload_lds16(Bg + (size_t)r * 256 + h2 * 32 + c4s * 8,                    \
                  &ldsB[BUF][(i * 256 + w * 64) * 8]);                         \
    }                                                                          \
  }

  f32x4 acc[4][4];
#pragma unroll
  for (int i = 0; i < 4; ++i)
#pragma unroll
    for (int j = 0; j < 4; ++j) acc[i][j] = (f32x4){0.f, 0.f, 0.f, 0.f};

  STAGE_AB(0, 0)
#pragma unroll
  for (int kt = 0; kt < 4; ++kt) {
    __syncthreads();
    if (kt < 3) STAGE_AB(kt + 1, (kt + 1) & 1)
    const u16* bA = ldsA[kt & 1];
    const u16* bB = ldsB[kt & 1];
#pragma unroll
    for (int hh = 0; hh < 2; ++hh) {
      s16x8 af[4], bfr[4];
#pragma unroll
      for (int mi = 0; mi < 4; ++mi)
        af[mi] = *(const s16x8*)&bA[(hh * 128 + wr * 64 + mi * 16 + lr) * 32 +
                                    (lk ^ sxor) * 8];
#pragma unroll
      for (int ni = 0; ni < 4; ++ni)
        bfr[ni] = *(const s16x8*)&bB[(hh * 128 + wc * 64 + ni * 16 + lr) * 32 +
                                     (lk ^ sxor) * 8];
#pragma unroll
      for (int mi = 0; mi < 4; ++mi)
#pragma unroll
        for (int ni = 0; ni < 4; ++ni)
          acc[mi][ni] = __builtin_amdgcn_mfma_f32_16x16x32_bf16(af[mi], bfr[ni],
                                                                acc[mi][ni], 0, 0, 0);
    }
  }
#undef STAGE_AB

#pragma unroll
  for (int mi = 0; mi < 4; ++mi) {
#pragma unroll
    for (int ni = 0; ni < 4; ++ni) {
      f32x4 v = acc[mi][ni];
      int r = m0 + wr * 64 + mi * 16 + lk * 4;
      int c = n0 + wc * 64 + ni * 16 + lr;
#pragma unroll
      for (int j = 0; j < 4; ++j)
        Cf[(size_t)(r + j) * 768 + c] = v[j];
    }
  }
}

// One-shot transpose-convert: WST (Ws^T), WXT, WHT, PRJ  (out[N][K] bf16 from in[K][N] f32)
__global__ void pack_all(const float* __restrict__ Ws, const float* __restrict__ wx,
                         const float* __restrict__ wh, const float* __restrict__ pw,
                         u16* __restrict__ WST, u16* __restrict__ WXT,
                         u16* __restrict__ WHT, u16* __restrict__ PRJ) {
  int idx = blockIdx.x * 256 + threadIdx.x;
  const float* src; u16* dst; int N; int li;
  if (idx < 65536)        { src = Ws; dst = WST; N = 256; li = idx; }
  else if (idx < 262144)  { src = wx; dst = WXT; N = 768; li = idx - 65536; }
  else if (idx < 458752)  { src = wh; dst = WHT; N = 768; li = idx - 262144; }
  else                    { src = pw; dst = PRJ; N = 256; li = idx - 458752; }
  int n = li >> 8, k = li & 255;
  dst[li] = f2bf(src[(size_t)k * N + n]);
}

// Fragment-major packing of [Wg | Ws] in 32-col strips for fused_step.
// chunk c: l=c&63, ni=(c>>6)&1, kc=(c>>7)&7, s=c>>10;
// BP[c][e] = bf16(W[kc*32+(l>>4)*8+e][s*32+ni*16+(l&15)]); strips 0-7=Wg, 8-15=Ws.
__global__ void pack_bp(const float* __restrict__ Wg, const float* __restrict__ Ws,
                        u16* __restrict__ BP) {
  int c = blockIdx.x * 256 + threadIdx.x;  // 16384 chunks
  int l = c & 63, ni = (c >> 6) & 1, kc = (c >> 7) & 7, s = c >> 10;
  int n = s * 32 + ni * 16 + (l & 15);
  int k0 = kc * 32 + (l >> 4) * 8;
  const float* W = (n < 256) ? Wg : Ws;
  int nn = n & 255;
  u16x8 o;
#pragma unroll
  for (int e = 0; e < 8; ++e) o[e] = f2bf(W[(size_t)(k0 + e) * 256 + nn]);
  *(u16x8*)(BP + (size_t)c * 8) = o;
}

// WGAD[d][h] = sum_j Wg[d][h*32+j] * adst[h*32+j]
__global__ void wgad_kernel(const float* __restrict__ Wg, const float* __restrict__ adst,
                            float* __restrict__ WGAD) {
  const int h = blockIdx.x, d = threadIdx.x;
  float s = 0.f;
#pragma unroll
  for (int j = 0; j < 32; ++j) s += Wg[(size_t)d * 256 + h * 32 + j] * adst[h * 32 + j];
  WGAD[(size_t)d * 8 + h] = s;
}

// x0 bf16 + virtual sum -> state f32/bf16 + ED (state . WGAD per head)
__global__ __launch_bounds__(256)
void prep_x_kernel(const float* __restrict__ nf, u16* __restrict__ X0,
                   float* __restrict__ state, u16* __restrict__ GS,
                   const float* __restrict__ WGAD, float* __restrict__ ED) {
  __shared__ f32x4 part[4][64];
  __shared__ float stt[256];
  __shared__ float red[4][8];
  const int b = blockIdx.x, t = threadIdx.x;
  const int c4 = t & 63, sg = t >> 6, l = t & 63;
  const f32x4* src = (const f32x4*)(nf + (size_t)b * 48 * 256);
  f32x4 acc = (f32x4){0.f, 0.f, 0.f, 0.f};
  for (int s = sg * 12; s < sg * 12 + 12; ++s) {
    f32x4 v = src[(size_t)s * 64 + c4];
    acc += v;
    u16x4 o = {f2bf(v[0]), f2bf(v[1]), f2bf(v[2]), f2bf(v[3])};
    *(u16x4*)(X0 + ((size_t)b * 48 + s) * 256 + c4 * 4) = o;
  }
  part[sg][c4] = acc;
  __syncthreads();
  if (t < 64) {
    f32x4 r = part[0][t] + part[1][t] + part[2][t] + part[3][t];
#pragma unroll
    for (int j = 0; j < 4; ++j) {
      int d = t * 4 + j;
      stt[d] = r[j];
      state[(size_t)b * 256 + d] = r[j];
      GS[(size_t)b * 512 + 256 + d] = f2bf(r[j]);
    }
  }
  __syncthreads();
  // ED phase
  const float st = stt[t];
  float pr[8];
#pragma unroll
  for (int h = 0; h < 8; ++h) pr[h] = redsum_wave(st * WGAD[(size_t)t * 8 + h]);
  if (l == 0) {
#pragma unroll
    for (int h = 0; h < 8; ++h) red[sg][h] = pr[h];
  }
  __syncthreads();
  if (t < 8) ED[(size_t)b * 8 + t] = red[0][t] + red[1][t] + red[2][t] + red[3][t];
}

// GRU elementwise + ED for next step
__global__ void gru_kernel(const float* __restrict__ G1, const float* __restrict__ G2,
                           const float* __restrict__ bx, const float* __restrict__ bh,
                           float* __restrict__ state, u16* __restrict__ GS,
                           const float* __restrict__ WGAD, float* __restrict__ ED) {
  __shared__ float red[4][8];
  const int b = blockIdx.x, d = threadIdx.x;
  const int wv = d >> 6, l = d & 63;
  const float* g1 = G1 + (size_t)b * 768;
  const float* g2 = G2 + (size_t)b * 768;
  float xz = g1[d] + bx[d], xr = g1[256 + d] + bx[256 + d], xh = g1[512 + d] + bx[512 + d];
  float hz = g2[d] + bh[d], hr = g2[256 + d] + bh[256 + d], hh2 = g2[512 + d] + bh[512 + d];
  float z = 1.f / (1.f + expf(-(xz + hz)));
  float r = 1.f / (1.f + expf(-(xr + hr)));
  float n = tanhf(xh + r * hh2);
  float h0 = state[b * 256 + d];
  float sn = z * h0 + (1.f - z) * n;
  state[b * 256 + d] = sn;
  GS[(size_t)b * 512 + 256 + d] = f2bf(sn);
  // ED for next step
  float pr[8];
#pragma unroll
  for (int h = 0; h < 8; ++h) pr[h] = redsum_wave(sn * WGAD[(size_t)d * 8 + h]);
  if (l == 0) {
#pragma unroll
    for (int h = 0; h < 8; ++h) red[wv][h] = pr[h];
  }
  __syncthreads();
  if (d < 8) ED[(size_t)b * 8 + d] = red[0][d] + red[1][d] + red[2][d] + red[3][d];
}

extern "C" void kernel_launch(void* const* d_in, const int* in_sizes, int n_in,
                              void* d_out, int out_size, void* d_ws, size_t ws_size,
                              hipStream_t stream) {
  const float* nf  = (const float*)d_in[0];
  const float* Wg  = (const float*)d_in[2];
  const float* Ws  = (const float*)d_in[3];
  const float* asr = (const float*)d_in[4];
  const float* ads = (const float*)d_in[5];
  const float* wx  = (const float*)d_in[6];
  const float* wh  = (const float*)d_in[7];
  const float* bx  = (const float*)d_in[8];
  const float* bh  = (const float*)d_in[9];
  const float* pw  = (const float*)d_in[10];
  const float* pb  = (const float*)d_in[11];
  float* out = (float*)d_out;

  char* p = (char*)d_ws;
  size_t off = 0;
  auto alloc = [&](size_t bytes) { char* r = p + off; off += (bytes + 255) & ~255ULL; return r; };
  u16* WST   = (u16*)alloc(256 * 256 * 2);
  u16* WXT   = (u16*)alloc(768 * 256 * 2);
  u16* WHT   = (u16*)alloc(768 * 256 * 2);
  u16* PRJ   = (u16*)alloc(256 * 256 * 2);
  u16* BP    = (u16*)alloc(512 * 256 * 2);            // [Wg|Ws] fragment-major strips
  float* WGAD = (float*)alloc(256 * 8 * 4);
  u16* X0    = (u16*)alloc((size_t)98304 * 256 * 2);
  u16* X1    = (u16*)alloc((size_t)98304 * 256 * 2);
  float* SV   = (float*)alloc((size_t)2048 * 256 * 4);
  float* ED   = (float*)alloc((size_t)2048 * 8 * 4);
  float* G1   = (float*)alloc((size_t)2048 * 768 * 4);
  float* G2   = (float*)alloc((size_t)2048 * 768 * 4);
  u16* GS     = (u16*)alloc((size_t)2048 * 512 * 2);  // [g0 | state] bf16
  float* ST   = (float*)alloc((size_t)2048 * 256 * 4);

  pack_all<<<2048, 256, 0, stream>>>(Ws, wx, wh, pw, WST, WXT, WHT, PRJ);
  pack_bp<<<64, 256, 0, stream>>>(Wg, Ws, BP);
  wgad_kernel<<<8, 256, 0, stream>>>(Wg, ads, WGAD);
  prep_x_kernel<<<2048, 256, 0, stream>>>(nf, X0, ST, GS, WGAD, ED);

  u16* xc = X0; u16* xn = X1;
  for (int t = 0; t < 4; ++t) {
    // sv = state @ Ws   (M=2048, N=256)
    gemm_bt<0><<<dim3(16, 2), 256, 0, stream>>>(GS + 256, 512, WST, SV, 256, nullptr);
    // fused: h + attention + g0 + xnext
    fused_step<<<512, 256, 0, stream>>>(xc, BP, SV, ED, asr, GS, (t < 3) ? xn : nullptr);
    // GRU gates (both in one launch)
    gemm_gates<<<dim3(16, 12), 256, 0, stream>>>(GS, WXT, WHT, G1, G2);
    // GRU elementwise + next-step e_dst
    gru_kernel<<<2048, 256, 0, stream>>>(G1, G2, bx, bh, ST, GS, WGAD, ED);
    u16* tmp = xc; xc = xn; xn = tmp;
  }
  // out = state @ proj_w + proj_b
  gemm_bt<2><<<dim3(16, 2), 256, 0, stream>>>(GS + 256, 512, PRJ, out, 256, pb);
}

// Round 9
// 290.592 us; speedup vs baseline: 3.0067x; 1.0035x over previous
//
#include <hip/hip_runtime.h>
#include <hip/hip_bf16.h>
#include <stdint.h>

// AttentiveFP readout: B=2048 graphs x (48 real + 1 virtual) nodes, D=256, H=8, DH=32, 4 steps.
// Round-9: round-8 structure + TRUE counted-vmcnt depth-2 stage pipeline in fused_step:
//  - 3 x 16KB LDS strip buffers; stages s and s+1 in flight at every iteration top.
//  - s_waitcnt vmcnt(N) where N = exact # of VMEM ops issued after the stage being consumed
//    (in-order vmcnt retirement => that stage is guaranteed resident; no full drain).
//  - Prologue global->reg loads (A frags, sv/ed/asrc) drained once before the pipeline so
//    the vmcnt domain contains only stage loads + epilogue stores (counted per strip type).
//  - e_dst folded via WGAD (= Wg @ adst) computed in prep/gru; sv via small GEMM; GRU gates
//    merged GEMM; final projection GEMM.

#define NEG_SLOPE 0.2f

typedef unsigned short u16;
typedef short s16x8 __attribute__((ext_vector_type(8)));
typedef float f32x4 __attribute__((ext_vector_type(4)));
typedef u16 u16x4 __attribute__((ext_vector_type(4)));
typedef u16 u16x8 __attribute__((ext_vector_type(8)));

__device__ __forceinline__ u16 f2bf(float f) {
  union { float f; uint32_t u; } v; v.f = f;
  uint32_t r = (v.u + 0x7FFFu + ((v.u >> 16) & 1u)) >> 16;  // RNE
  return (u16)r;
}
__device__ __forceinline__ float bf2f(u16 h) {
  union { uint32_t u; float f; } v; v.u = ((uint32_t)h) << 16;
  return v.f;
}

__device__ __forceinline__ void gload_lds16(const void* g, void* l) {
  __builtin_amdgcn_global_load_lds(
      (const __attribute__((address_space(1))) void*)g,
      (__attribute__((address_space(3))) void*)l, 16, 0, 0);
}

__device__ __forceinline__ float redsum_lr(float v) {
  v += __shfl_xor(v, 1); v += __shfl_xor(v, 2);
  v += __shfl_xor(v, 4); v += __shfl_xor(v, 8);
  return v;
}
__device__ __forceinline__ float redsum_lk(float v) {
  v += __shfl_xor(v, 16); v += __shfl_xor(v, 32);
  return v;
}
__device__ __forceinline__ float redmax_lk(float v) {
  v = fmaxf(v, __shfl_xor(v, 16)); v = fmaxf(v, __shfl_xor(v, 32));
  return v;
}
__device__ __forceinline__ float redsum_wave(float v) {
  v += __shfl_xor(v, 1); v += __shfl_xor(v, 2); v += __shfl_xor(v, 4);
  v += __shfl_xor(v, 8); v += __shfl_xor(v, 16); v += __shfl_xor(v, 32);
  return v;
}

// ---------------------------------------------------------------------------
// FUSED step: 512 blocks x 256 threads; wave w handles graph blockIdx*4+w.
// NS strips of 32 cols (16KB); strip s<8 = attention head s (Wg), s>=8 = Xn (Ws).
// Depth-2 counted-vmcnt pipeline over 3 LDS buffers.
// ---------------------------------------------------------------------------
template<int NS>
__global__ __launch_bounds__(256, 2)
void fused_step(const u16* __restrict__ X, const u16* __restrict__ BP,
                const float* __restrict__ SV, const float* __restrict__ ED,
                const float* __restrict__ asrc, u16* __restrict__ GS,
                u16* __restrict__ Xn) {
  __shared__ u16 ldsB[3][8192];  // 3 x 16KB strip buffers (fragment-major)
  const int tid = threadIdx.x;
  const int w = tid >> 6, l = tid & 63, lr = l & 15, lk = l >> 4;
  const int b = blockIdx.x * 4 + w;
  const u16* Xg = X + (size_t)b * 48 * 256;

#define STAGE(S, BUF)                                                          \
  {                                                                            \
    _Pragma("unroll") for (int i_ = 0; i_ < 4; ++i_)                           \
        gload_lds16(BP + ((size_t)(S)*1024 + i_ * 256 + tid) * 8,              \
                    &ldsB[BUF][(i_ * 256 + w * 64) * 8]);                      \
  }

  // ---- prologue: ALL global->reg loads, then one drain, then the pipeline ----
  s16x8 af[8][3];
#pragma unroll
  for (int kc = 0; kc < 8; ++kc)
#pragma unroll
    for (int mi = 0; mi < 3; ++mi)
      af[kc][mi] = *(const s16x8*)(Xg + (size_t)(mi * 16 + lr) * 256 + kc * 32 + lk * 8);

  float ed8[8], asA[8], asB[8], svA[8][2];
#pragma unroll
  for (int h = 0; h < 8; ++h) {
    ed8[h] = ED[(size_t)b * 8 + h];
    asA[h] = asrc[h * 32 + lr];
    asB[h] = asrc[h * 32 + 16 + lr];
#pragma unroll
    for (int ni = 0; ni < 2; ++ni)
      svA[h][ni] = SV[(size_t)b * 256 + h * 32 + ni * 16 + lr];
  }
  asm volatile("s_waitcnt vmcnt(0)" ::: "memory");  // vmcnt domain now stage-only

  STAGE(0, 0)
  STAGE(1, 1)

#pragma unroll
  for (int s = 0; s < NS; ++s) {
    // Need STAGE(s) resident. Ops younger than STAGE(s) at this point:
    //   STAGE(s+1) [4 loads, if issued] + stores of strip s-1 [2 attn / 24 Xn].
    // In-order vmcnt retirement => wait vmcnt(younger-count) guarantees STAGE(s) done.
    if (s == 0)              { asm volatile("s_waitcnt vmcnt(4)" ::: "memory"); }
    else if (s + 1 < NS) {
      if (s - 1 < 8)         { asm volatile("s_waitcnt vmcnt(6)" ::: "memory"); }
      else                   { asm volatile("s_waitcnt vmcnt(28)" ::: "memory"); }
    } else                   { asm volatile("s_waitcnt vmcnt(0)" ::: "memory"); }
    __builtin_amdgcn_s_barrier();
    if (s + 2 < NS) STAGE(s + 2, (s + 2) % 3)

    f32x4 acc[3][2];
#pragma unroll
    for (int mi = 0; mi < 3; ++mi)
#pragma unroll
      for (int ni = 0; ni < 2; ++ni) acc[mi][ni] = (f32x4){0.f, 0.f, 0.f, 0.f};

    const u16* bufB = ldsB[s % 3];
#pragma unroll
    for (int kc = 0; kc < 8; ++kc) {
      s16x8 bfr[2];
#pragma unroll
      for (int ni = 0; ni < 2; ++ni)
        bfr[ni] = *(const s16x8*)&bufB[((kc * 2 + ni) * 64 + l) * 8];
#pragma unroll
      for (int mi = 0; mi < 3; ++mi)
#pragma unroll
        for (int ni = 0; ni < 2; ++ni)
          acc[mi][ni] = __builtin_amdgcn_mfma_f32_16x16x32_bf16(
              af[kc][mi], bfr[ni], acc[mi][ni], 0, 0, 0);
    }

    if (s < 8) {
      // ---- attention for head s (strip cols = head s's 32 dims): 2 GS stores ----
      float al[3][4];
      float m = -1e30f;
#pragma unroll
      for (int mi = 0; mi < 3; ++mi)
#pragma unroll
        for (int j = 0; j < 4; ++j) {
          float p = acc[mi][0][j] * asA[s] + acc[mi][1][j] * asB[s];
          p = redsum_lr(p) + ed8[s];           // e = e_src + e_dst
          p = (p > 0.f) ? p : NEG_SLOPE * p;   // leaky_relu
          al[mi][j] = p;
          m = fmaxf(m, p);
        }
      m = redmax_lk(m);  // max over all 48 nodes
      float sm = 0.f;
#pragma unroll
      for (int mi = 0; mi < 3; ++mi)
#pragma unroll
        for (int j = 0; j < 4; ++j) {
          float ex = expf(al[mi][j] - m);
          al[mi][j] = ex; sm += ex;
        }
      sm = redsum_lk(sm);
      const float inv = 1.f / sm;
#pragma unroll
      for (int ni = 0; ni < 2; ++ni) {
        float mm = 0.f;
#pragma unroll
        for (int mi = 0; mi < 3; ++mi)
#pragma unroll
          for (int j = 0; j < 4; ++j) mm += al[mi][j] * acc[mi][ni][j];
        mm = redsum_lk(mm) * inv;  // msg over 48 nodes
        if (lk == 0)
          GS[(size_t)b * 512 + s * 32 + ni * 16 + lr] =
              f2bf(fmaxf(mm + svA[s][ni], 0.f));  // g0 = relu(msg + sv)
      }
    } else {
      // ---- Ws strip: relu -> Xn: 24 scalar stores ----
#pragma unroll
      for (int mi = 0; mi < 3; ++mi)
#pragma unroll
        for (int ni = 0; ni < 2; ++ni)
#pragma unroll
          for (int j = 0; j < 4; ++j)
            Xn[(size_t)(b * 48 + mi * 16 + lk * 4 + j) * 256 + (s - 8) * 32 +
               ni * 16 + lr] = f2bf(fmaxf(acc[mi][ni][j], 0.f));
    }
  }
#undef STAGE
}

// ---------------------------------------------------------------------------
// Generic bf16 GEMM: C[M,N] = A[M,K=256] * Bt[N,K=256]^T, 128x128, pipelined.
// EPI: 0 = f32 store; 2 = f32 + bias (projection).
// ---------------------------------------------------------------------------
template<int EPI>
__global__ __launch_bounds__(256)
void gemm_bt(const u16* __restrict__ A, int lda,
             const u16* __restrict__ Bt,
             float* __restrict__ Cf, int ldc, const float* __restrict__ bias) {
  __shared__ u16 ldsA[2][2 * 128 * 32];
  __shared__ u16 ldsB[2][2 * 128 * 32];
  const int tid = threadIdx.x;
  const int w = tid >> 6, l = tid & 63;
  const int wr = w >> 1, wc = w & 1;
  const int lr = l & 15, lk = l >> 4;
  const int sxor = (lr >> 1) & 3;
  const int m0 = blockIdx.x * 128, n0 = blockIdx.y * 128;

#define STAGE_AB(KT, BUF)                                                      \
  {                                                                            \
    const u16* Ag = A + (size_t)m0 * lda + (KT)*64;                            \
    const u16* Bg = Bt + (size_t)n0 * 256 + (KT)*64;                           \
    _Pragma("unroll") for (int i = 0; i < 4; ++i) {                            \
      int q = i * 256 + tid;                                                   \
      int h2 = q >> 9, r = (q >> 2) & 127, c4 = q & 3;                         \
      int c4s = c4 ^ ((r >> 1) & 3);                                           \
      gload_lds16(Ag + (size_t)r * lda + h2 * 32 + c4s * 8,                    \
                  &ldsA[BUF][(i * 256 + w * 64) * 8]);                         \
      gload_lds16(Bg + (size_t)r * 256 + h2 * 32 + c4s * 8,                    \
                  &ldsB[BUF][(i * 256 + w * 64) * 8]);                         \
    }                                                                          \
  }

  f32x4 acc[4][4];
#pragma unroll
  for (int i = 0; i < 4; ++i)
#pragma unroll
    for (int j = 0; j < 4; ++j) acc[i][j] = (f32x4){0.f, 0.f, 0.f, 0.f};

  STAGE_AB(0, 0)
#pragma unroll
  for (int kt = 0; kt < 4; ++kt) {
    __syncthreads();
    if (kt < 3) STAGE_AB(kt + 1, (kt + 1) & 1)
    const u16* bA = ldsA[kt & 1];
    const u16* bB = ldsB[kt & 1];
#pragma unroll
    for (int hh = 0; hh < 2; ++hh) {
      s16x8 af[4], bfr[4];
#pragma unroll
      for (int mi = 0; mi < 4; ++mi)
        af[mi] = *(const s16x8*)&bA[(hh * 128 + wr * 64 + mi * 16 + lr) * 32 +
                                    (lk ^ sxor) * 8];
#pragma unroll
      for (int ni = 0; ni < 4; ++ni)
        bfr[ni] = *(const s16x8*)&bB[(hh * 128 + wc * 64 + ni * 16 + lr) * 32 +
                                     (lk ^ sxor) * 8];
#pragma unroll
      for (int mi = 0; mi < 4; ++mi)
#pragma unroll
        for (int ni = 0; ni < 4; ++ni)
          acc[mi][ni] = __builtin_amdgcn_mfma_f32_16x16x32_bf16(af[mi], bfr[ni],
                                                                acc[mi][ni], 0, 0, 0);
    }
  }
#undef STAGE_AB

#pragma unroll
  for (int mi = 0; mi < 4; ++mi) {
#pragma unroll
    for (int ni = 0; ni < 4; ++ni) {
      f32x4 v = acc[mi][ni];
      int r = m0 + wr * 64 + mi * 16 + lk * 4;
      int c = n0 + wc * 64 + ni * 16 + lr;
#pragma unroll
      for (int j = 0; j < 4; ++j) {
        float fv = v[j];
        if (EPI == 0) Cf[(size_t)(r + j) * ldc + c] = fv;
        else          Cf[(size_t)(r + j) * ldc + c] = fv + bias[c];
      }
    }
  }
}

// Merged GRU-gate GEMM: blockIdx.y<6 -> G1 = g0@wx ; else G2 = state@wh. Pipelined.
__global__ __launch_bounds__(256)
void gemm_gates(const u16* __restrict__ GS, const u16* __restrict__ WXT,
                const u16* __restrict__ WHT, float* __restrict__ G1,
                float* __restrict__ G2) {
  __shared__ u16 ldsA[2][2 * 128 * 32];
  __shared__ u16 ldsB[2][2 * 128 * 32];
  const bool second = blockIdx.y >= 6;
  const u16* A = GS + (second ? 256 : 0);
  const u16* Bt = second ? WHT : WXT;
  float* Cf = second ? G2 : G1;
  const int n0 = (second ? blockIdx.y - 6 : blockIdx.y) * 128;
  const int m0 = blockIdx.x * 128;
  const int tid = threadIdx.x;
  const int w = tid >> 6, l = tid & 63;
  const int wr = w >> 1, wc = w & 1;
  const int lr = l & 15, lk = l >> 4;
  const int sxor = (lr >> 1) & 3;

#define STAGE_AB(KT, BUF)                                                      \
  {                                                                            \
    const u16* Ag = A + (size_t)m0 * 512 + (KT)*64;                            \
    const u16* Bg = Bt + (size_t)n0 * 256 + (KT)*64;                           \
    _Pragma("unroll") for (int i = 0; i < 4; ++i) {                            \
      int q = i * 256 + tid;                                                   \
      int h2 = q >> 9, r = (q >> 2) & 127, c4 = q & 3;                         \
      int c4s = c4 ^ ((r >> 1) & 3);                                           \
      gload_lds16(Ag + (size_t)r * 512 + h2 * 32 + c4s * 8,                    \
                  &ldsA[BUF][(i * 256 + w * 64) * 8]);                         \
      gload_lds16(Bg + (size_t)r * 256 + h2 * 32 + c4s * 8,                    \
                  &ldsB[BUF][(i * 256 + w * 64) * 8]);                         \
    }                                                                          \
  }

  f32x4 acc[4][4];
#pragma unroll
  for (int i = 0; i < 4; ++i)
#pragma unroll
    for (int j = 0; j < 4; ++j) acc[i][j] = (f32x4){0.f, 0.f, 0.f, 0.f};

  STAGE_AB(0, 0)
#pragma unroll
  for (int kt = 0; kt < 4; ++kt) {
    __syncthreads();
    if (kt < 3) STAGE_AB(kt + 1, (kt + 1) & 1)
    const u16* bA = ldsA[kt & 1];
    const u16* bB = ldsB[kt & 1];
#pragma unroll
    for (int hh = 0; hh < 2; ++hh) {
      s16x8 af[4], bfr[4];
#pragma unroll
      for (int mi = 0; mi < 4; ++mi)
        af[mi] = *(const s16x8*)&bA[(hh * 128 + wr * 64 + mi * 16 + lr) * 32 +
                                    (lk ^ sxor) * 8];
#pragma unroll
      for (int ni = 0; ni < 4; ++ni)
        bfr[ni] = *(const s16x8*)&bB[(hh * 128 + wc * 64 + ni * 16 + lr) * 32 +
                                     (lk ^ sxor) * 8];
#pragma unroll
      for (int mi = 0; mi < 4; ++mi)
#pragma unroll
        for (int ni = 0; ni < 4; ++ni)
          acc[mi][ni] = __builtin_amdgcn_mfma_f32_16x16x32_bf16(af[mi], bfr[ni],
                                                                acc[mi][ni], 0, 0, 0);
    }
  }
#undef STAGE_AB

#pragma unroll
  for (int mi = 0; mi < 4; ++mi) {
#pragma unroll
    for (int ni = 0; ni < 4; ++ni) {
      f32x4 v = acc[mi][ni];
      int r = m0 + wr * 64 + mi * 16 + lk * 4;
      int c = n0 + wc * 64 + ni * 16 + lr;
#pragma unroll
      for (int j = 0; j < 4; ++j)
        Cf[(size_t)(r + j) * 768 + c] = v[j];
    }
  }
}

// One-shot transpose-convert: WST (Ws^T), WXT, WHT, PRJ  (out[N][K] bf16 from in[K][N] f32)
__global__ void pack_all(const float* __restrict__ Ws, const float* __restrict__ wx,
                         const float* __restrict__ wh, const float* __restrict__ pw,
                         u16* __restrict__ WST, u16* __restrict__ WXT,
                         u16* __restrict__ WHT, u16* __restrict__ PRJ) {
  int idx = blockIdx.x * 256 + threadIdx.x;
  const float* src; u16* dst; int N; int li;
  if (idx < 65536)        { src = Ws; dst = WST; N = 256; li = idx; }
  else if (idx < 262144)  { src = wx; dst = WXT; N = 768; li = idx - 65536; }
  else if (idx < 458752)  { src = wh; dst = WHT; N = 768; li = idx - 262144; }
  else                    { src = pw; dst = PRJ; N = 256; li = idx - 458752; }
  int n = li >> 8, k = li & 255;
  dst[li] = f2bf(src[(size_t)k * N + n]);
}

// Fragment-major packing of [Wg | Ws] in 32-col strips for fused_step.
__global__ void pack_bp(const float* __restrict__ Wg, const float* __restrict__ Ws,
                        u16* __restrict__ BP) {
  int c = blockIdx.x * 256 + threadIdx.x;  // 16384 chunks
  int l = c & 63, ni = (c >> 6) & 1, kc = (c >> 7) & 7, s = c >> 10;
  int n = s * 32 + ni * 16 + (l & 15);
  int k0 = kc * 32 + (l >> 4) * 8;
  const float* W = (n < 256) ? Wg : Ws;
  int nn = n & 255;
  u16x8 o;
#pragma unroll
  for (int e = 0; e < 8; ++e) o[e] = f2bf(W[(size_t)(k0 + e) * 256 + nn]);
  *(u16x8*)(BP + (size_t)c * 8) = o;
}

// WGAD[d][h] = sum_j Wg[d][h*32+j] * adst[h*32+j]
__global__ void wgad_kernel(const float* __restrict__ Wg, const float* __restrict__ adst,
                            float* __restrict__ WGAD) {
  const int h = blockIdx.x, d = threadIdx.x;
  float s = 0.f;
#pragma unroll
  for (int j = 0; j < 32; ++j) s += Wg[(size_t)d * 256 + h * 32 + j] * adst[h * 32 + j];
  WGAD[(size_t)d * 8 + h] = s;
}

// x0 bf16 + virtual sum -> state f32/bf16 + ED (state . WGAD per head)
__global__ __launch_bounds__(256)
void prep_x_kernel(const float* __restrict__ nf, u16* __restrict__ X0,
                   float* __restrict__ state, u16* __restrict__ GS,
                   const float* __restrict__ WGAD, float* __restrict__ ED) {
  __shared__ f32x4 part[4][64];
  __shared__ float stt[256];
  __shared__ float red[4][8];
  const int b = blockIdx.x, t = threadIdx.x;
  const int c4 = t & 63, sg = t >> 6, l = t & 63;
  const f32x4* src = (const f32x4*)(nf + (size_t)b * 48 * 256);
  f32x4 acc = (f32x4){0.f, 0.f, 0.f, 0.f};
  for (int s = sg * 12; s < sg * 12 + 12; ++s) {
    f32x4 v = src[(size_t)s * 64 + c4];
    acc += v;
    u16x4 o = {f2bf(v[0]), f2bf(v[1]), f2bf(v[2]), f2bf(v[3])};
    *(u16x4*)(X0 + ((size_t)b * 48 + s) * 256 + c4 * 4) = o;
  }
  part[sg][c4] = acc;
  __syncthreads();
  if (t < 64) {
    f32x4 r = part[0][t] + part[1][t] + part[2][t] + part[3][t];
#pragma unroll
    for (int j = 0; j < 4; ++j) {
      int d = t * 4 + j;
      stt[d] = r[j];
      state[(size_t)b * 256 + d] = r[j];
      GS[(size_t)b * 512 + 256 + d] = f2bf(r[j]);
    }
  }
  __syncthreads();
  const float st = stt[t];
  float pr[8];
#pragma unroll
  for (int h = 0; h < 8; ++h) pr[h] = redsum_wave(st * WGAD[(size_t)t * 8 + h]);
  if (l == 0) {
#pragma unroll
    for (int h = 0; h < 8; ++h) red[sg][h] = pr[h];
  }
  __syncthreads();
  if (t < 8) ED[(size_t)b * 8 + t] = red[0][t] + red[1][t] + red[2][t] + red[3][t];
}

// GRU elementwise + ED for next step
__global__ void gru_kernel(const float* __restrict__ G1, const float* __restrict__ G2,
                           const float* __restrict__ bx, const float* __restrict__ bh,
                           float* __restrict__ state, u16* __restrict__ GS,
                           const float* __restrict__ WGAD, float* __restrict__ ED) {
  __shared__ float red[4][8];
  const int b = blockIdx.x, d = threadIdx.x;
  const int wv = d >> 6, l = d & 63;
  const float* g1 = G1 + (size_t)b * 768;
  const float* g2 = G2 + (size_t)b * 768;
  float xz = g1[d] + bx[d], xr = g1[256 + d] + bx[256 + d], xh = g1[512 + d] + bx[512 + d];
  float hz = g2[d] + bh[d], hr = g2[256 + d] + bh[256 + d], hh2 = g2[512 + d] + bh[512 + d];
  float z = 1.f / (1.f + expf(-(xz + hz)));
  float r = 1.f / (1.f + expf(-(xr + hr)));
  float n = tanhf(xh + r * hh2);
  float h0 = state[b * 256 + d];
  float sn = z * h0 + (1.f - z) * n;
  state[b * 256 + d] = sn;
  GS[(size_t)b * 512 + 256 + d] = f2bf(sn);
  float pr[8];
#pragma unroll
  for (int h = 0; h < 8; ++h) pr[h] = redsum_wave(sn * WGAD[(size_t)d * 8 + h]);
  if (l == 0) {
#pragma unroll
    for (int h = 0; h < 8; ++h) red[wv][h] = pr[h];
  }
  __syncthreads();
  if (d < 8) ED[(size_t)b * 8 + d] = red[0][d] + red[1][d] + red[2][d] + red[3][d];
}

extern "C" void kernel_launch(void* const* d_in, const int* in_sizes, int n_in,
                              void* d_out, int out_size, void* d_ws, size_t ws_size,
                              hipStream_t stream) {
  const float* nf  = (const float*)d_in[0];
  const float* Wg  = (const float*)d_in[2];
  const float* Ws  = (const float*)d_in[3];
  const float* asr = (const float*)d_in[4];
  const float* ads = (const float*)d_in[5];
  const float* wx  = (const float*)d_in[6];
  const float* wh  = (const float*)d_in[7];
  const float* bx  = (const float*)d_in[8];
  const float* bh  = (const float*)d_in[9];
  const float* pw  = (const float*)d_in[10];
  const float* pb  = (const float*)d_in[11];
  float* out = (float*)d_out;

  char* p = (char*)d_ws;
  size_t off = 0;
  auto alloc = [&](size_t bytes) { char* r = p + off; off += (bytes + 255) & ~255ULL; return r; };
  u16* WST   = (u16*)alloc(256 * 256 * 2);
  u16* WXT   = (u16*)alloc(768 * 256 * 2);
  u16* WHT   = (u16*)alloc(768 * 256 * 2);
  u16* PRJ   = (u16*)alloc(256 * 256 * 2);
  u16* BP    = (u16*)alloc(512 * 256 * 2);            // [Wg|Ws] fragment-major strips
  float* WGAD = (float*)alloc(256 * 8 * 4);
  u16* X0    = (u16*)alloc((size_t)98304 * 256 * 2);
  u16* X1    = (u16*)alloc((size_t)98304 * 256 * 2);
  float* SV   = (float*)alloc((size_t)2048 * 256 * 4);
  float* ED   = (float*)alloc((size_t)2048 * 8 * 4);
  float* G1   = (float*)alloc((size_t)2048 * 768 * 4);
  float* G2   = (float*)alloc((size_t)2048 * 768 * 4);
  u16* GS     = (u16*)alloc((size_t)2048 * 512 * 2);  // [g0 | state] bf16
  float* ST   = (float*)alloc((size_t)2048 * 256 * 4);

  pack_all<<<2048, 256, 0, stream>>>(Ws, wx, wh, pw, WST, WXT, WHT, PRJ);
  pack_bp<<<64, 256, 0, stream>>>(Wg, Ws, BP);
  wgad_kernel<<<8, 256, 0, stream>>>(Wg, ads, WGAD);
  prep_x_kernel<<<2048, 256, 0, stream>>>(nf, X0, ST, GS, WGAD, ED);

  u16* xc = X0; u16* xn = X1;
  for (int t = 0; t < 4; ++t) {
    // sv = state @ Ws   (M=2048, N=256)
    gemm_bt<0><<<dim3(16, 2), 256, 0, stream>>>(GS + 256, 512, WST, SV, 256, nullptr);
    // fused: h + attention + g0 (+ xnext for t<3)
    if (t < 3) fused_step<16><<<512, 256, 0, stream>>>(xc, BP, SV, ED, asr, GS, xn);
    else       fused_step<8><<<512, 256, 0, stream>>>(xc, BP, SV, ED, asr, GS, nullptr);
    // GRU gates (both in one launch)
    gemm_gates<<<dim3(16, 12), 256, 0, stream>>>(GS, WXT, WHT, G1, G2);
    // GRU elementwise + next-step e_dst
    gru_kernel<<<2048, 256, 0, stream>>>(G1, G2, bx, bh, ST, GS, WGAD, ED);
    u16* tmp = xc; xc = xn; xn = tmp;
  }
  // out = state @ proj_w + proj_b
  gemm_bt<2><<<dim3(16, 2), 256, 0, stream>>>(GS + 256, 512, PRJ, out, 256, pb);
}

// Round 10
// 290.038 us; speedup vs baseline: 3.0125x; 1.0019x over previous
//
#include <hip/hip_runtime.h>
#include <hip/hip_bf16.h>
#include <stdint.h>

// AttentiveFP readout: B=2048 graphs x (48 real + 1 virtual) nodes, D=256, H=8, DH=32, 4 steps.
// Round-10: kill the attention-VALU critical path by folding e_src into the GEMM:
//   e_src[b,node,h] = x @ WGAS[:,h],  WGAS = sum_j Wg[:,h*32+j]*asrc[h*32+j] (precomputed).
//   A 24-MFMA "E-phase" produces all 48x8 logits; softmax once per wave (8 lanes, lk-shfl)
//   -> normalized alpha table in LDS; per-strip attention = 12 broadcast LDS reads + FMA.
// fused_step: 4 graphs/block (wave=graph), A in regs, B strips 16KB double-buffered with
// counted vmcnt; 3 blocks/CU (LDS 38.9KB). e_dst folded via WGAD (in prep/gru); sv via
// small GEMM; merged gates GEMM; projection GEMM.

#define NEG_SLOPE 0.2f

typedef unsigned short u16;
typedef short s16x8 __attribute__((ext_vector_type(8)));
typedef float f32x4 __attribute__((ext_vector_type(4)));
typedef u16 u16x4 __attribute__((ext_vector_type(4)));
typedef u16 u16x8 __attribute__((ext_vector_type(8)));

__device__ __forceinline__ u16 f2bf(float f) {
  union { float f; uint32_t u; } v; v.f = f;
  uint32_t r = (v.u + 0x7FFFu + ((v.u >> 16) & 1u)) >> 16;  // RNE
  return (u16)r;
}
__device__ __forceinline__ float bf2f(u16 h) {
  union { uint32_t u; float f; } v; v.u = ((uint32_t)h) << 16;
  return v.f;
}

__device__ __forceinline__ void gload_lds16(const void* g, void* l) {
  __builtin_amdgcn_global_load_lds(
      (const __attribute__((address_space(1))) void*)g,
      (__attribute__((address_space(3))) void*)l, 16, 0, 0);
}

__device__ __forceinline__ float redsum_lk(float v) {
  v += __shfl_xor(v, 16); v += __shfl_xor(v, 32);
  return v;
}
__device__ __forceinline__ float redmax_lk(float v) {
  v = fmaxf(v, __shfl_xor(v, 16)); v = fmaxf(v, __shfl_xor(v, 32));
  return v;
}
__device__ __forceinline__ float redsum_wave(float v) {
  v += __shfl_xor(v, 1); v += __shfl_xor(v, 2); v += __shfl_xor(v, 4);
  v += __shfl_xor(v, 8); v += __shfl_xor(v, 16); v += __shfl_xor(v, 32);
  return v;
}

// ---------------------------------------------------------------------------
// FUSED step: 512 blocks x 256 threads; wave w handles graph blockIdx*4+w.
// NS strips of 32 cols (16KB); strip s<8 = attention head s (Wg), s>=8 = Xn (Ws).
// E-phase (24 MFMA on WGAS frags) -> alpha table in LDS -> cheap per-strip msg.
// ---------------------------------------------------------------------------
template<int NS>
__global__ __launch_bounds__(256, 3)
void fused_step(const u16* __restrict__ X, const u16* __restrict__ BP,
                const u16* __restrict__ EP, const float* __restrict__ SV,
                const float* __restrict__ ED, u16* __restrict__ GS,
                u16* __restrict__ Xn) {
  __shared__ u16 ldsB[2][8192];        // 2 x 16KB strip buffers (fragment-major)
  __shared__ float alphaL[4][8][48];   // per-wave normalized attention weights
  const int tid = threadIdx.x;
  const int w = tid >> 6, l = tid & 63, lr = l & 15, lk = l >> 4;
  const int b = blockIdx.x * 4 + w;
  const u16* Xg = X + (size_t)b * 48 * 256;

#define STAGE(S, BUF)                                                          \
  {                                                                            \
    _Pragma("unroll") for (int i_ = 0; i_ < 4; ++i_)                           \
        gload_lds16(BP + ((size_t)(S)*1024 + i_ * 256 + tid) * 8,              \
                    &ldsB[BUF][(i_ * 256 + w * 64) * 8]);                      \
  }

  // ---- prologue: all global->reg loads, one drain ----
  s16x8 af[8][3];
#pragma unroll
  for (int kc = 0; kc < 8; ++kc)
#pragma unroll
    for (int mi = 0; mi < 3; ++mi)
      af[kc][mi] = *(const s16x8*)(Xg + (size_t)(mi * 16 + lr) * 256 + kc * 32 + lk * 8);

  s16x8 be[8];
#pragma unroll
  for (int kc = 0; kc < 8; ++kc)
    be[kc] = *(const s16x8*)(EP + ((size_t)kc * 64 + l) * 8);

  const float edv = ED[(size_t)b * 8 + (l & 7)];
  float svA[8][2];
#pragma unroll
  for (int h = 0; h < 8; ++h)
#pragma unroll
    for (int ni = 0; ni < 2; ++ni)
      svA[h][ni] = SV[(size_t)b * 256 + h * 32 + ni * 16 + lr];

  asm volatile("s_waitcnt vmcnt(0)" ::: "memory");  // vmcnt domain now stage/store-only
  STAGE(0, 0)

  // ---- E-phase: e_src for all 48 nodes x 8 heads via 24 MFMA (hides stage-0) ----
  {
    f32x4 ae[3];
#pragma unroll
    for (int mi = 0; mi < 3; ++mi) ae[mi] = (f32x4){0.f, 0.f, 0.f, 0.f};
#pragma unroll
    for (int kc = 0; kc < 8; ++kc)
#pragma unroll
      for (int mi = 0; mi < 3; ++mi)
        ae[mi] = __builtin_amdgcn_mfma_f32_16x16x32_bf16(af[kc][mi], be[kc], ae[mi], 0, 0, 0);

    if (lr < 8) {  // lane lr owns head lr for its lk-row-group
      float ev[3][4];
      float m = -1e30f;
#pragma unroll
      for (int mi = 0; mi < 3; ++mi)
#pragma unroll
        for (int j = 0; j < 4; ++j) {
          float v = ae[mi][j] + edv;
          v = (v > 0.f) ? v : NEG_SLOPE * v;  // leaky_relu
          ev[mi][j] = v;
          m = fmaxf(m, v);
        }
      m = redmax_lk(m);  // max over all 48 nodes (partners lk^1/lk^2 also lr<8)
      float sm = 0.f;
#pragma unroll
      for (int mi = 0; mi < 3; ++mi)
#pragma unroll
        for (int j = 0; j < 4; ++j) {
          float ex = expf(ev[mi][j] - m);
          ev[mi][j] = ex; sm += ex;
        }
      sm = redsum_lk(sm);
      const float inv = 1.f / sm;
#pragma unroll
      for (int mi = 0; mi < 3; ++mi)
#pragma unroll
        for (int j = 0; j < 4; ++j)
          alphaL[w][lr][mi * 16 + lk * 4 + j] = ev[mi][j] * inv;
    }
  }

  // ---- strip pipeline: 2 buffers, stage s+1 after barrier of s, counted vmcnt ----
#pragma unroll
  for (int s = 0; s < NS; ++s) {
    // Need STAGE(s) resident. Younger-than-STAGE(s) VMEM: stores of strip s-1
    // (2 GS for attn strips, 24 Xn for Ws strips); s==0 has nothing younger.
    if (s == 0)      { asm volatile("s_waitcnt vmcnt(0)" ::: "memory"); }
    else if (s <= 8) { asm volatile("s_waitcnt vmcnt(2)" ::: "memory"); }
    else             { asm volatile("s_waitcnt vmcnt(24)" ::: "memory"); }
    __builtin_amdgcn_s_barrier();
    if (s + 1 < NS) STAGE(s + 1, (s + 1) & 1)

    f32x4 acc[3][2];
#pragma unroll
    for (int mi = 0; mi < 3; ++mi)
#pragma unroll
      for (int ni = 0; ni < 2; ++ni) acc[mi][ni] = (f32x4){0.f, 0.f, 0.f, 0.f};

    const u16* bufB = ldsB[s & 1];
#pragma unroll
    for (int kc = 0; kc < 8; ++kc) {
      s16x8 bfr[2];
#pragma unroll
      for (int ni = 0; ni < 2; ++ni)
        bfr[ni] = *(const s16x8*)&bufB[((kc * 2 + ni) * 64 + l) * 8];
#pragma unroll
      for (int mi = 0; mi < 3; ++mi)
#pragma unroll
        for (int ni = 0; ni < 2; ++ni)
          acc[mi][ni] = __builtin_amdgcn_mfma_f32_16x16x32_bf16(
              af[kc][mi], bfr[ni], acc[mi][ni], 0, 0, 0);
    }

    if (s < 8) {
      // ---- msg for head s: alpha from LDS (broadcast reads), 2 GS stores ----
      float mm0 = 0.f, mm1 = 0.f;
#pragma unroll
      for (int mi = 0; mi < 3; ++mi)
#pragma unroll
        for (int j = 0; j < 4; ++j) {
          const float a = alphaL[w][s][mi * 16 + lk * 4 + j];
          mm0 += a * acc[mi][0][j];
          mm1 += a * acc[mi][1][j];
        }
      mm0 = redsum_lk(mm0);
      mm1 = redsum_lk(mm1);
      if (lk == 0) {
        GS[(size_t)b * 512 + s * 32 + lr]      = f2bf(fmaxf(mm0 + svA[s][0], 0.f));
        GS[(size_t)b * 512 + s * 32 + 16 + lr] = f2bf(fmaxf(mm1 + svA[s][1], 0.f));
      }
    } else {
      // ---- Ws strip: relu -> Xn (24 stores) ----
#pragma unroll
      for (int mi = 0; mi < 3; ++mi)
#pragma unroll
        for (int ni = 0; ni < 2; ++ni)
#pragma unroll
          for (int j = 0; j < 4; ++j)
            Xn[(size_t)(b * 48 + mi * 16 + lk * 4 + j) * 256 + (s - 8) * 32 +
               ni * 16 + lr] = f2bf(fmaxf(acc[mi][ni][j], 0.f));
    }
  }
#undef STAGE
}

// ---------------------------------------------------------------------------
// Generic bf16 GEMM: C[M,N] = A[M,K=256] * Bt[N,K=256]^T, 128x128, pipelined.
// EPI: 0 = f32 store; 2 = f32 + bias (projection).
// ---------------------------------------------------------------------------
template<int EPI>
__global__ __launch_bounds__(256)
void gemm_bt(const u16* __restrict__ A, int lda,
             const u16* __restrict__ Bt,
             float* __restrict__ Cf, int ldc, const float* __restrict__ bias) {
  __shared__ u16 ldsA[2][2 * 128 * 32];
  __shared__ u16 ldsB[2][2 * 128 * 32];
  const int tid = threadIdx.x;
  const int w = tid >> 6, l = tid & 63;
  const int wr = w >> 1, wc = w & 1;
  const int lr = l & 15, lk = l >> 4;
  const int sxor = (lr >> 1) & 3;
  const int m0 = blockIdx.x * 128, n0 = blockIdx.y * 128;

#define STAGE_AB(KT, BUF)                                                      \
  {                                                                            \
    const u16* Ag = A + (size_t)m0 * lda + (KT)*64;                            \
    const u16* Bg = Bt + (size_t)n0 * 256 + (KT)*64;                           \
    _Pragma("unroll") for (int i = 0; i < 4; ++i) {                            \
      int q = i * 256 + tid;                                                   \
      int h2 = q >> 9, r = (q >> 2) & 127, c4 = q & 3;                         \
      int c4s = c4 ^ ((r >> 1) & 3);                                           \
      gload_lds16(Ag + (size_t)r * lda + h2 * 32 + c4s * 8,                    \
                  &ldsA[BUF][(i * 256 + w * 64) * 8]);                         \
      gload_lds16(Bg + (size_t)r * 256 + h2 * 32 + c4s * 8,                    \
                  &ldsB[BUF][(i * 256 + w * 64) * 8]);                         \
    }                                                                          \
  }

  f32x4 acc[4][4];
#pragma unroll
  for (int i = 0; i < 4; ++i)
#pragma unroll
    for (int j = 0; j < 4; ++j) acc[i][j] = (f32x4){0.f, 0.f, 0.f, 0.f};

  STAGE_AB(0, 0)
#pragma unroll
  for (int kt = 0; kt < 4; ++kt) {
    __syncthreads();
    if (kt < 3) STAGE_AB(kt + 1, (kt + 1) & 1)
    const u16* bA = ldsA[kt & 1];
    const u16* bB = ldsB[kt & 1];
#pragma unroll
    for (int hh = 0; hh < 2; ++hh) {
      s16x8 af[4], bfr[4];
#pragma unroll
      for (int mi = 0; mi < 4; ++mi)
        af[mi] = *(const s16x8*)&bA[(hh * 128 + wr * 64 + mi * 16 + lr) * 32 +
                                    (lk ^ sxor) * 8];
#pragma unroll
      for (int ni = 0; ni < 4; ++ni)
        bfr[ni] = *(const s16x8*)&bB[(hh * 128 + wc * 64 + ni * 16 + lr) * 32 +
                                     (lk ^ sxor) * 8];
#pragma unroll
      for (int mi = 0; mi < 4; ++mi)
#pragma unroll
        for (int ni = 0; ni < 4; ++ni)
          acc[mi][ni] = __builtin_amdgcn_mfma_f32_16x16x32_bf16(af[mi], bfr[ni],
                                                                acc[mi][ni], 0, 0, 0);
    }
  }
#undef STAGE_AB

#pragma unroll
  for (int mi = 0; mi < 4; ++mi) {
#pragma unroll
    for (int ni = 0; ni < 4; ++ni) {
      f32x4 v = acc[mi][ni];
      int r = m0 + wr * 64 + mi * 16 + lk * 4;
      int c = n0 + wc * 64 + ni * 16 + lr;
#pragma unroll
      for (int j = 0; j < 4; ++j) {
        float fv = v[j];
        if (EPI == 0) Cf[(size_t)(r + j) * ldc + c] = fv;
        else          Cf[(size_t)(r + j) * ldc + c] = fv + bias[c];
      }
    }
  }
}

// Merged GRU-gate GEMM: blockIdx.y<6 -> G1 = g0@wx ; else G2 = state@wh. Pipelined.
__global__ __launch_bounds__(256)
void gemm_gates(const u16* __restrict__ GS, const u16* __restrict__ WXT,
                const u16* __restrict__ WHT, float* __restrict__ G1,
                float* __restrict__ G2) {
  __shared__ u16 ldsA[2][2 * 128 * 32];
  __shared__ u16 ldsB[2][2 * 128 * 32];
  const bool second = blockIdx.y >= 6;
  const u16* A = GS + (second ? 256 : 0);
  const u16* Bt = second ? WHT : WXT;
  float* Cf = second ? G2 : G1;
  const int n0 = (second ? blockIdx.y - 6 : blockIdx.y) * 128;
  const int m0 = blockIdx.x * 128;
  const int tid = threadIdx.x;
  const int w = tid >> 6, l = tid & 63;
  const int wr = w >> 1, wc = w & 1;
  const int lr = l & 15, lk = l >> 4;
  const int sxor = (lr >> 1) & 3;

#define STAGE_AB(KT, BUF)                                                      \
  {                                                                            \
    const u16* Ag = A + (size_t)m0 * 512 + (KT)*64;                            \
    const u16* Bg = Bt + (size_t)n0 * 256 + (KT)*64;                           \
    _Pragma("unroll") for (int i = 0; i < 4; ++i) {                            \
      int q = i * 256 + tid;                                                   \
      int h2 = q >> 9, r = (q >> 2) & 127, c4 = q & 3;                         \
      int c4s = c4 ^ ((r >> 1) & 3);                                           \
      gload_lds16(Ag + (size_t)r * 512 + h2 * 32 + c4s * 8,                    \
                  &ldsA[BUF][(i * 256 + w * 64) * 8]);                         \
      gload_lds16(Bg + (size_t)r * 256 + h2 * 32 + c4s * 8,                    \
                  &ldsB[BUF][(i * 256 + w * 64) * 8]);                         \
    }                                                                          \
  }

  f32x4 acc[4][4];
#pragma unroll
  for (int i = 0; i < 4; ++i)
#pragma unroll
    for (int j = 0; j < 4; ++j) acc[i][j] = (f32x4){0.f, 0.f, 0.f, 0.f};

  STAGE_AB(0, 0)
#pragma unroll
  for (int kt = 0; kt < 4; ++kt) {
    __syncthreads();
    if (kt < 3) STAGE_AB(kt + 1, (kt + 1) & 1)
    const u16* bA = ldsA[kt & 1];
    const u16* bB = ldsB[kt & 1];
#pragma unroll
    for (int hh = 0; hh < 2; ++hh) {
      s16x8 af[4], bfr[4];
#pragma unroll
      for (int mi = 0; mi < 4; ++mi)
        af[mi] = *(const s16x8*)&bA[(hh * 128 + wr * 64 + mi * 16 + lr) * 32 +
                                    (lk ^ sxor) * 8];
#pragma unroll
      for (int ni = 0; ni < 4; ++ni)
        bfr[ni] = *(const s16x8*)&bB[(hh * 128 + wc * 64 + ni * 16 + lr) * 32 +
                                     (lk ^ sxor) * 8];
#pragma unroll
      for (int mi = 0; mi < 4; ++mi)
#pragma unroll
        for (int ni = 0; ni < 4; ++ni)
          acc[mi][ni] = __builtin_amdgcn_mfma_f32_16x16x32_bf16(af[mi], bfr[ni],
                                                                acc[mi][ni], 0, 0, 0);
    }
  }
#undef STAGE_AB

#pragma unroll
  for (int mi = 0; mi < 4; ++mi) {
#pragma unroll
    for (int ni = 0; ni < 4; ++ni) {
      f32x4 v = acc[mi][ni];
      int r = m0 + wr * 64 + mi * 16 + lk * 4;
      int c = n0 + wc * 64 + ni * 16 + lr;
#pragma unroll
      for (int j = 0; j < 4; ++j)
        Cf[(size_t)(r + j) * 768 + c] = v[j];
    }
  }
}

// One-shot transpose-convert: WST (Ws^T), WXT, WHT, PRJ  (out[N][K] bf16 from in[K][N] f32)
__global__ void pack_all(const float* __restrict__ Ws, const float* __restrict__ wx,
                         const float* __restrict__ wh, const float* __restrict__ pw,
                         u16* __restrict__ WST, u16* __restrict__ WXT,
                         u16* __restrict__ WHT, u16* __restrict__ PRJ) {
  int idx = blockIdx.x * 256 + threadIdx.x;
  const float* src; u16* dst; int N; int li;
  if (idx < 65536)        { src = Ws; dst = WST; N = 256; li = idx; }
  else if (idx < 262144)  { src = wx; dst = WXT; N = 768; li = idx - 65536; }
  else if (idx < 458752)  { src = wh; dst = WHT; N = 768; li = idx - 262144; }
  else                    { src = pw; dst = PRJ; N = 256; li = idx - 458752; }
  int n = li >> 8, k = li & 255;
  dst[li] = f2bf(src[(size_t)k * N + n]);
}

// Fragment-major packing of [Wg | Ws] in 32-col strips for fused_step.
__global__ void pack_bp(const float* __restrict__ Wg, const float* __restrict__ Ws,
                        u16* __restrict__ BP) {
  int c = blockIdx.x * 256 + threadIdx.x;  // 16384 chunks
  int l = c & 63, ni = (c >> 6) & 1, kc = (c >> 7) & 7, s = c >> 10;
  int n = s * 32 + ni * 16 + (l & 15);
  int k0 = kc * 32 + (l >> 4) * 8;
  const float* W = (n < 256) ? Wg : Ws;
  int nn = n & 255;
  u16x8 o;
#pragma unroll
  for (int e = 0; e < 8; ++e) o[e] = f2bf(W[(size_t)(k0 + e) * 256 + nn]);
  *(u16x8*)(BP + (size_t)c * 8) = o;
}

// WGAD[d][h] = sum_j Wg[d][h*32+j]*adst[h*32+j];  WGAS likewise with asrc.
__global__ void wgad_kernel(const float* __restrict__ Wg, const float* __restrict__ adst,
                            const float* __restrict__ asrc,
                            float* __restrict__ WGAD, float* __restrict__ WGAS) {
  const int h = blockIdx.x, d = threadIdx.x;
  float sd = 0.f, ss = 0.f;
#pragma unroll
  for (int j = 0; j < 32; ++j) {
    float wv = Wg[(size_t)d * 256 + h * 32 + j];
    sd += wv * adst[h * 32 + j];
    ss += wv * asrc[h * 32 + j];
  }
  WGAD[(size_t)d * 8 + h] = sd;
  WGAS[(size_t)d * 8 + h] = ss;
}

// B-fragment pack of WGAS for the E-phase MFMA (heads at cols 0-7; cols 8-15 zero).
__global__ void pack_ep(const float* __restrict__ WGAS, u16* __restrict__ EP) {
  int c = blockIdx.x * 256 + threadIdx.x;  // 512 chunks
  if (c >= 512) return;
  int l = c & 63, kc = c >> 6;
  int hh = l & 15, k0 = kc * 32 + (l >> 4) * 8;
  u16x8 o;
#pragma unroll
  for (int e = 0; e < 8; ++e)
    o[e] = (hh < 8) ? f2bf(WGAS[(size_t)(k0 + e) * 8 + hh]) : (u16)0;
  *(u16x8*)(EP + (size_t)c * 8) = o;
}

// x0 bf16 + virtual sum -> state f32/bf16 + ED (state . WGAD per head)
__global__ __launch_bounds__(256)
void prep_x_kernel(const float* __restrict__ nf, u16* __restrict__ X0,
                   float* __restrict__ state, u16* __restrict__ GS,
                   const float* __restrict__ WGAD, float* __restrict__ ED) {
  __shared__ f32x4 part[4][64];
  __shared__ float stt[256];
  __shared__ float red[4][8];
  const int b = blockIdx.x, t = threadIdx.x;
  const int c4 = t & 63, sg = t >> 6, l = t & 63;
  const f32x4* src = (const f32x4*)(nf + (size_t)b * 48 * 256);
  f32x4 acc = (f32x4){0.f, 0.f, 0.f, 0.f};
  for (int s = sg * 12; s < sg * 12 + 12; ++s) {
    f32x4 v = src[(size_t)s * 64 + c4];
    acc += v;
    u16x4 o = {f2bf(v[0]), f2bf(v[1]), f2bf(v[2]), f2bf(v[3])};
    *(u16x4*)(X0 + ((size_t)b * 48 + s) * 256 + c4 * 4) = o;
  }
  part[sg][c4] = acc;
  __syncthreads();
  if (t < 64) {
    f32x4 r = part[0][t] + part[1][t] + part[2][t] + part[3][t];
#pragma unroll
    for (int j = 0; j < 4; ++j) {
      int d = t * 4 + j;
      stt[d] = r[j];
      state[(size_t)b * 256 + d] = r[j];
      GS[(size_t)b * 512 + 256 + d] = f2bf(r[j]);
    }
  }
  __syncthreads();
  const float st = stt[t];
  float pr[8];
#pragma unroll
  for (int h = 0; h < 8; ++h) pr[h] = redsum_wave(st * WGAD[(size_t)t * 8 + h]);
  if (l == 0) {
#pragma unroll
    for (int h = 0; h < 8; ++h) red[sg][h] = pr[h];
  }
  __syncthreads();
  if (t < 8) ED[(size_t)b * 8 + t] = red[0][t] + red[1][t] + red[2][t] + red[3][t];
}

// GRU elementwise + ED for next step
__global__ void gru_kernel(const float* __restrict__ G1, const float* __restrict__ G2,
                           const float* __restrict__ bx, const float* __restrict__ bh,
                           float* __restrict__ state, u16* __restrict__ GS,
                           const float* __restrict__ WGAD, float* __restrict__ ED) {
  __shared__ float red[4][8];
  const int b = blockIdx.x, d = threadIdx.x;
  const int wv = d >> 6, l = d & 63;
  const float* g1 = G1 + (size_t)b * 768;
  const float* g2 = G2 + (size_t)b * 768;
  float xz = g1[d] + bx[d], xr = g1[256 + d] + bx[256 + d], xh = g1[512 + d] + bx[512 + d];
  float hz = g2[d] + bh[d], hr = g2[256 + d] + bh[256 + d], hh2 = g2[512 + d] + bh[512 + d];
  float z = 1.f / (1.f + expf(-(xz + hz)));
  float r = 1.f / (1.f + expf(-(xr + hr)));
  float n = tanhf(xh + r * hh2);
  float h0 = state[b * 256 + d];
  float sn = z * h0 + (1.f - z) * n;
  state[b * 256 + d] = sn;
  GS[(size_t)b * 512 + 256 + d] = f2bf(sn);
  float pr[8];
#pragma unroll
  for (int h = 0; h < 8; ++h) pr[h] = redsum_wave(sn * WGAD[(size_t)d * 8 + h]);
  if (l == 0) {
#pragma unroll
    for (int h = 0; h < 8; ++h) red[wv][h] = pr[h];
  }
  __syncthreads();
  if (d < 8) ED[(size_t)b * 8 + d] = red[0][d] + red[1][d] + red[2][d] + red[3][d];
}

extern "C" void kernel_launch(void* const* d_in, const int* in_sizes, int n_in,
                              void* d_out, int out_size, void* d_ws, size_t ws_size,
                              hipStream_t stream) {
  const float* nf  = (const float*)d_in[0];
  const float* Wg  = (const float*)d_in[2];
  const float* Ws  = (const float*)d_in[3];
  const float* asr = (const float*)d_in[4];
  const float* ads = (const float*)d_in[5];
  const float* wx  = (const float*)d_in[6];
  const float* wh  = (const float*)d_in[7];
  const float* bx  = (const float*)d_in[8];
  const float* bh  = (const float*)d_in[9];
  const float* pw  = (const float*)d_in[10];
  const float* pb  = (const float*)d_in[11];
  float* out = (float*)d_out;

  char* p = (char*)d_ws;
  size_t off = 0;
  auto alloc = [&](size_t bytes) { char* r = p + off; off += (bytes + 255) & ~255ULL; return r; };
  u16* WST   = (u16*)alloc(256 * 256 * 2);
  u16* WXT   = (u16*)alloc(768 * 256 * 2);
  u16* WHT   = (u16*)alloc(768 * 256 * 2);
  u16* PRJ   = (u16*)alloc(256 * 256 * 2);
  u16* BP    = (u16*)alloc(512 * 256 * 2);            // [Wg|Ws] fragment-major strips
  u16* EP    = (u16*)alloc(512 * 8 * 2);              // WGAS fragment pack (8KB)
  float* WGAD = (float*)alloc(256 * 8 * 4);
  float* WGAS = (float*)alloc(256 * 8 * 4);
  u16* X0    = (u16*)alloc((size_t)98304 * 256 * 2);
  u16* X1    = (u16*)alloc((size_t)98304 * 256 * 2);
  float* SV   = (float*)alloc((size_t)2048 * 256 * 4);
  float* ED   = (float*)alloc((size_t)2048 * 8 * 4);
  float* G1   = (float*)alloc((size_t)2048 * 768 * 4);
  float* G2   = (float*)alloc((size_t)2048 * 768 * 4);
  u16* GS     = (u16*)alloc((size_t)2048 * 512 * 2);  // [g0 | state] bf16
  float* ST   = (float*)alloc((size_t)2048 * 256 * 4);

  pack_all<<<2048, 256, 0, stream>>>(Ws, wx, wh, pw, WST, WXT, WHT, PRJ);
  pack_bp<<<64, 256, 0, stream>>>(Wg, Ws, BP);
  wgad_kernel<<<8, 256, 0, stream>>>(Wg, ads, asr, WGAD, WGAS);
  pack_ep<<<2, 256, 0, stream>>>(WGAS, EP);
  prep_x_kernel<<<2048, 256, 0, stream>>>(nf, X0, ST, GS, WGAD, ED);

  u16* xc = X0; u16* xn = X1;
  for (int t = 0; t < 4; ++t) {
    // sv = state @ Ws   (M=2048, N=256)
    gemm_bt<0><<<dim3(16, 2), 256, 0, stream>>>(GS + 256, 512, WST, SV, 256, nullptr);
    // fused: h + E-phase attention + g0 (+ xnext for t<3)
    if (t < 3) fused_step<16><<<512, 256, 0, stream>>>(xc, BP, EP, SV, ED, GS, xn);
    else       fused_step<8><<<512, 256, 0, stream>>>(xc, BP, EP, SV, ED, GS, nullptr);
    // GRU gates (both in one launch)
    gemm_gates<<<dim3(16, 12), 256, 0, stream>>>(GS, WXT, WHT, G1, G2);
    // GRU elementwise + next-step e_dst
    gru_kernel<<<2048, 256, 0, stream>>>(G1, G2, bx, bh, ST, GS, WGAD, ED);
    u16* tmp = xc; xc = xn; xn = tmp;
  }
  // out = state @ proj_w + proj_b
  gemm_bt<2><<<dim3(16, 2), 256, 0, stream>>>(GS + 256, 512, PRJ, out, 256, pb);
}

// Round 11
// 253.982 us; speedup vs baseline: 3.4401x; 1.1420x over previous
//
#include <hip/hip_runtime.h>
#include <hip/hip_bf16.h>
#include <stdint.h>

// AttentiveFP readout: B=2048 graphs x (48 real + 1 virtual) nodes, D=256, H=8, DH=32, 4 steps.
// Round-11: round-10 algorithm (E-phase folded attention, WGAD/WGAS folds) with fused_step
// restructured for latency: 128-thread blocks (2 waves, 1 graph/wave), grid 1024,
// __launch_bounds__(128,2) so A-fragments (96 VGPR) stay register-resident (round-10's
// VGPR=84 proved the compiler was reloading A from global every strip), 4 blocks/CU
// (35.8KB LDS) = 4 independent barrier pipelines. Even/odd B-col packing makes epilogue
// stores u16x2 (12 instead of 24 scalar stores). Counted vmcnt: 0 / 1 (attn) / 12 (Xn).

#define NEG_SLOPE 0.2f

typedef unsigned short u16;
typedef short s16x8 __attribute__((ext_vector_type(8)));
typedef float f32x4 __attribute__((ext_vector_type(4)));
typedef float f32x2 __attribute__((ext_vector_type(2)));
typedef u16 u16x2 __attribute__((ext_vector_type(2)));
typedef u16 u16x4 __attribute__((ext_vector_type(4)));
typedef u16 u16x8 __attribute__((ext_vector_type(8)));

__device__ __forceinline__ u16 f2bf(float f) {
  union { float f; uint32_t u; } v; v.f = f;
  uint32_t r = (v.u + 0x7FFFu + ((v.u >> 16) & 1u)) >> 16;  // RNE
  return (u16)r;
}
__device__ __forceinline__ float bf2f(u16 h) {
  union { uint32_t u; float f; } v; v.u = ((uint32_t)h) << 16;
  return v.f;
}

__device__ __forceinline__ void gload_lds16(const void* g, void* l) {
  __builtin_amdgcn_global_load_lds(
      (const __attribute__((address_space(1))) void*)g,
      (__attribute__((address_space(3))) void*)l, 16, 0, 0);
}

__device__ __forceinline__ float redsum_lk(float v) {
  v += __shfl_xor(v, 16); v += __shfl_xor(v, 32);
  return v;
}
__device__ __forceinline__ float redmax_lk(float v) {
  v = fmaxf(v, __shfl_xor(v, 16)); v = fmaxf(v, __shfl_xor(v, 32));
  return v;
}
__device__ __forceinline__ float redsum_wave(float v) {
  v += __shfl_xor(v, 1); v += __shfl_xor(v, 2); v += __shfl_xor(v, 4);
  v += __shfl_xor(v, 8); v += __shfl_xor(v, 16); v += __shfl_xor(v, 32);
  return v;
}

// ---------------------------------------------------------------------------
// FUSED step: 1024 blocks x 128 threads (2 waves); wave w owns graph blockIdx*2+w.
// NS strips of 32 cols (16KB); strip s<8 = attention head s (Wg), s>=8 = Xn (Ws).
// B cols packed even/odd: lane lr's ni=0 slot = col 2*lr, ni=1 slot = col 2*lr+1.
// ---------------------------------------------------------------------------
template<int NS>
__global__ __launch_bounds__(128, 2)
void fused_step(const u16* __restrict__ X, const u16* __restrict__ BP,
                const u16* __restrict__ EP, const float* __restrict__ SV,
                const float* __restrict__ ED, u16* __restrict__ GS,
                u16* __restrict__ Xn) {
  __shared__ u16 ldsB[2][8192];        // 2 x 16KB strip buffers (fragment-major)
  __shared__ float alphaL[2][8][48];   // per-wave normalized attention weights
  const int tid = threadIdx.x;
  const int w = tid >> 6, l = tid & 63, lr = l & 15, lk = l >> 4;
  const int b = blockIdx.x * 2 + w;
  const u16* Xg = X + (size_t)b * 48 * 256;

#define STAGE(S, BUF)                                                          \
  {                                                                            \
    _Pragma("unroll") for (int i_ = 0; i_ < 8; ++i_)                           \
        gload_lds16(BP + ((size_t)(S)*1024 + i_ * 128 + tid) * 8,              \
                    &ldsB[BUF][(i_ * 128 + w * 64) * 8]);                      \
  }

  // ---- prologue: all global->reg loads, one drain ----
  s16x8 af[8][3];
#pragma unroll
  for (int kc = 0; kc < 8; ++kc)
#pragma unroll
    for (int mi = 0; mi < 3; ++mi)
      af[kc][mi] = *(const s16x8*)(Xg + (size_t)(mi * 16 + lr) * 256 + kc * 32 + lk * 8);

  s16x8 be[8];
#pragma unroll
  for (int kc = 0; kc < 8; ++kc)
    be[kc] = *(const s16x8*)(EP + ((size_t)kc * 64 + l) * 8);

  const float edv = ED[(size_t)b * 8 + (l & 7)];
  f32x2 svA[8];
#pragma unroll
  for (int h = 0; h < 8; ++h)
    svA[h] = *(const f32x2*)(SV + (size_t)b * 256 + h * 32 + 2 * lr);

  asm volatile("s_waitcnt vmcnt(0)" ::: "memory");  // vmcnt domain now stage/store-only
  STAGE(0, 0)

  // ---- E-phase: e_src for all 48 nodes x 8 heads via 24 MFMA (hides stage-0) ----
  {
    f32x4 ae[3];
#pragma unroll
    for (int mi = 0; mi < 3; ++mi) ae[mi] = (f32x4){0.f, 0.f, 0.f, 0.f};
#pragma unroll
    for (int kc = 0; kc < 8; ++kc)
#pragma unroll
      for (int mi = 0; mi < 3; ++mi)
        ae[mi] = __builtin_amdgcn_mfma_f32_16x16x32_bf16(af[kc][mi], be[kc], ae[mi], 0, 0, 0);

    if (lr < 8) {  // lane lr owns head lr for its lk-row-group
      float ev[3][4];
      float m = -1e30f;
#pragma unroll
      for (int mi = 0; mi < 3; ++mi)
#pragma unroll
        for (int j = 0; j < 4; ++j) {
          float v = ae[mi][j] + edv;
          v = (v > 0.f) ? v : NEG_SLOPE * v;  // leaky_relu
          ev[mi][j] = v;
          m = fmaxf(m, v);
        }
      m = redmax_lk(m);  // max over all 48 nodes
      float sm = 0.f;
#pragma unroll
      for (int mi = 0; mi < 3; ++mi)
#pragma unroll
        for (int j = 0; j < 4; ++j) {
          float ex = expf(ev[mi][j] - m);
          ev[mi][j] = ex; sm += ex;
        }
      sm = redsum_lk(sm);
      const float inv = 1.f / sm;
#pragma unroll
      for (int mi = 0; mi < 3; ++mi)
#pragma unroll
        for (int j = 0; j < 4; ++j)
          alphaL[w][lr][mi * 16 + lk * 4 + j] = ev[mi][j] * inv;
    }
  }

  // ---- strip pipeline: 2 buffers, stage s+1 after barrier of s, counted vmcnt ----
#pragma unroll
  for (int s = 0; s < NS; ++s) {
    // Need STAGE(s) resident. Younger VMEM at this point: stores of strip s-1
    // (1 GS u16x2 for attn strips, 12 Xn u16x2 for Ws strips); s==0: nothing.
    if (s == 0)      { asm volatile("s_waitcnt vmcnt(0)" ::: "memory"); }
    else if (s <= 8) { asm volatile("s_waitcnt vmcnt(1)" ::: "memory"); }
    else             { asm volatile("s_waitcnt vmcnt(12)" ::: "memory"); }
    __builtin_amdgcn_s_barrier();
    if (s + 1 < NS) STAGE(s + 1, (s + 1) & 1)

    f32x4 acc[3][2];
#pragma unroll
    for (int mi = 0; mi < 3; ++mi)
#pragma unroll
      for (int ni = 0; ni < 2; ++ni) acc[mi][ni] = (f32x4){0.f, 0.f, 0.f, 0.f};

    const u16* bufB = ldsB[s & 1];
#pragma unroll
    for (int kc = 0; kc < 8; ++kc) {
      s16x8 bfr[2];
#pragma unroll
      for (int ni = 0; ni < 2; ++ni)
        bfr[ni] = *(const s16x8*)&bufB[((kc * 2 + ni) * 64 + l) * 8];
#pragma unroll
      for (int mi = 0; mi < 3; ++mi)
#pragma unroll
        for (int ni = 0; ni < 2; ++ni)
          acc[mi][ni] = __builtin_amdgcn_mfma_f32_16x16x32_bf16(
              af[kc][mi], bfr[ni], acc[mi][ni], 0, 0, 0);
    }

    if (s < 8) {
      // ---- msg for head s (cols 2lr, 2lr+1): alpha broadcast reads, 1 u16x2 store ----
      float mm0 = 0.f, mm1 = 0.f;
#pragma unroll
      for (int mi = 0; mi < 3; ++mi)
#pragma unroll
        for (int j = 0; j < 4; ++j) {
          const float a = alphaL[w][s][mi * 16 + lk * 4 + j];
          mm0 += a * acc[mi][0][j];
          mm1 += a * acc[mi][1][j];
        }
      mm0 = redsum_lk(mm0);
      mm1 = redsum_lk(mm1);
      if (lk == 0) {
        u16x2 o = {f2bf(fmaxf(mm0 + svA[s][0], 0.f)),
                   f2bf(fmaxf(mm1 + svA[s][1], 0.f))};
        *(u16x2*)(GS + (size_t)b * 512 + s * 32 + 2 * lr) = o;
      }
    } else {
      // ---- Ws strip: relu -> Xn (12 u16x2 stores) ----
#pragma unroll
      for (int mi = 0; mi < 3; ++mi)
#pragma unroll
        for (int j = 0; j < 4; ++j) {
          u16x2 o = {f2bf(fmaxf(acc[mi][0][j], 0.f)),
                     f2bf(fmaxf(acc[mi][1][j], 0.f))};
          *(u16x2*)(Xn + (size_t)(b * 48 + mi * 16 + lk * 4 + j) * 256 +
                    (s - 8) * 32 + 2 * lr) = o;
        }
    }
  }
#undef STAGE
}

// ---------------------------------------------------------------------------
// Generic bf16 GEMM: C[M,N] = A[M,K=256] * Bt[N,K=256]^T, 128x128, pipelined.
// EPI: 0 = f32 store; 2 = f32 + bias (projection).
// ---------------------------------------------------------------------------
template<int EPI>
__global__ __launch_bounds__(256)
void gemm_bt(const u16* __restrict__ A, int lda,
             const u16* __restrict__ Bt,
             float* __restrict__ Cf, int ldc, const float* __restrict__ bias) {
  __shared__ u16 ldsA[2][2 * 128 * 32];
  __shared__ u16 ldsB[2][2 * 128 * 32];
  const int tid = threadIdx.x;
  const int w = tid >> 6, l = tid & 63;
  const int wr = w >> 1, wc = w & 1;
  const int lr = l & 15, lk = l >> 4;
  const int sxor = (lr >> 1) & 3;
  const int m0 = blockIdx.x * 128, n0 = blockIdx.y * 128;

#define STAGE_AB(KT, BUF)                                                      \
  {                                                                            \
    const u16* Ag = A + (size_t)m0 * lda + (KT)*64;                            \
    const u16* Bg = Bt + (size_t)n0 * 256 + (KT)*64;                           \
    _Pragma("unroll") for (int i = 0; i < 4; ++i) {                            \
      int q = i * 256 + tid;                                                   \
      int h2 = q >> 9, r = (q >> 2) & 127, c4 = q & 3;                         \
      int c4s = c4 ^ ((r >> 1) & 3);                                           \
      gload_lds16(Ag + (size_t)r * lda + h2 * 32 + c4s * 8,                    \
                  &ldsA[BUF][(i * 256 + w * 64) * 8]);                         \
      gload_lds16(Bg + (size_t)r * 256 + h2 * 32 + c4s * 8,                    \
                  &ldsB[BUF][(i * 256 + w * 64) * 8]);                         \
    }                                                                          \
  }

  f32x4 acc[4][4];
#pragma unroll
  for (int i = 0; i < 4; ++i)
#pragma unroll
    for (int j = 0; j < 4; ++j) acc[i][j] = (f32x4){0.f, 0.f, 0.f, 0.f};

  STAGE_AB(0, 0)
#pragma unroll
  for (int kt = 0; kt < 4; ++kt) {
    __syncthreads();
    if (kt < 3) STAGE_AB(kt + 1, (kt + 1) & 1)
    const u16* bA = ldsA[kt & 1];
    const u16* bB = ldsB[kt & 1];
#pragma unroll
    for (int hh = 0; hh < 2; ++hh) {
      s16x8 af[4], bfr[4];
#pragma unroll
      for (int mi = 0; mi < 4; ++mi)
        af[mi] = *(const s16x8*)&bA[(hh * 128 + wr * 64 + mi * 16 + lr) * 32 +
                                    (lk ^ sxor) * 8];
#pragma unroll
      for (int ni = 0; ni < 4; ++ni)
        bfr[ni] = *(const s16x8*)&bB[(hh * 128 + wc * 64 + ni * 16 + lr) * 32 +
                                     (lk ^ sxor) * 8];
#pragma unroll
      for (int mi = 0; mi < 4; ++mi)
#pragma unroll
        for (int ni = 0; ni < 4; ++ni)
          acc[mi][ni] = __builtin_amdgcn_mfma_f32_16x16x32_bf16(af[mi], bfr[ni],
                                                                acc[mi][ni], 0, 0, 0);
    }
  }
#undef STAGE_AB

#pragma unroll
  for (int mi = 0; mi < 4; ++mi) {
#pragma unroll
    for (int ni = 0; ni < 4; ++ni) {
      f32x4 v = acc[mi][ni];
      int r = m0 + wr * 64 + mi * 16 + lk * 4;
      int c = n0 + wc * 64 + ni * 16 + lr;
#pragma unroll
      for (int j = 0; j < 4; ++j) {
        float fv = v[j];
        if (EPI == 0) Cf[(size_t)(r + j) * ldc + c] = fv;
        else          Cf[(size_t)(r + j) * ldc + c] = fv + bias[c];
      }
    }
  }
}

// Merged GRU-gate GEMM: blockIdx.y<6 -> G1 = g0@wx ; else G2 = state@wh. Pipelined.
__global__ __launch_bounds__(256)
void gemm_gates(const u16* __restrict__ GS, const u16* __restrict__ WXT,
                const u16* __restrict__ WHT, float* __restrict__ G1,
                float* __restrict__ G2) {
  __shared__ u16 ldsA[2][2 * 128 * 32];
  __shared__ u16 ldsB[2][2 * 128 * 32];
  const bool second = blockIdx.y >= 6;
  const u16* A = GS + (second ? 256 : 0);
  const u16* Bt = second ? WHT : WXT;
  float* Cf = second ? G2 : G1;
  const int n0 = (second ? blockIdx.y - 6 : blockIdx.y) * 128;
  const int m0 = blockIdx.x * 128;
  const int tid = threadIdx.x;
  const int w = tid >> 6, l = tid & 63;
  const int wr = w >> 1, wc = w & 1;
  const int lr = l & 15, lk = l >> 4;
  const int sxor = (lr >> 1) & 3;

#define STAGE_AB(KT, BUF)                                                      \
  {                                                                            \
    const u16* Ag = A + (size_t)m0 * 512 + (KT)*64;                            \
    const u16* Bg = Bt + (size_t)n0 * 256 + (KT)*64;                           \
    _Pragma("unroll") for (int i = 0; i < 4; ++i) {                            \
      int q = i * 256 + tid;                                                   \
      int h2 = q >> 9, r = (q >> 2) & 127, c4 = q & 3;                         \
      int c4s = c4 ^ ((r >> 1) & 3);                                           \
      gload_lds16(Ag + (size_t)r * 512 + h2 * 32 + c4s * 8,                    \
                  &ldsA[BUF][(i * 256 + w * 64) * 8]);                         \
      gload_lds16(Bg + (size_t)r * 256 + h2 * 32 + c4s * 8,                    \
                  &ldsB[BUF][(i * 256 + w * 64) * 8]);                         \
    }                                                                          \
  }

  f32x4 acc[4][4];
#pragma unroll
  for (int i = 0; i < 4; ++i)
#pragma unroll
    for (int j = 0; j < 4; ++j) acc[i][j] = (f32x4){0.f, 0.f, 0.f, 0.f};

  STAGE_AB(0, 0)
#pragma unroll
  for (int kt = 0; kt < 4; ++kt) {
    __syncthreads();
    if (kt < 3) STAGE_AB(kt + 1, (kt + 1) & 1)
    const u16* bA = ldsA[kt & 1];
    const u16* bB = ldsB[kt & 1];
#pragma unroll
    for (int hh = 0; hh < 2; ++hh) {
      s16x8 af[4], bfr[4];
#pragma unroll
      for (int mi = 0; mi < 4; ++mi)
        af[mi] = *(const s16x8*)&bA[(hh * 128 + wr * 64 + mi * 16 + lr) * 32 +
                                    (lk ^ sxor) * 8];
#pragma unroll
      for (int ni = 0; ni < 4; ++ni)
        bfr[ni] = *(const s16x8*)&bB[(hh * 128 + wc * 64 + ni * 16 + lr) * 32 +
                                     (lk ^ sxor) * 8];
#pragma unroll
      for (int mi = 0; mi < 4; ++mi)
#pragma unroll
        for (int ni = 0; ni < 4; ++ni)
          acc[mi][ni] = __builtin_amdgcn_mfma_f32_16x16x32_bf16(af[mi], bfr[ni],
                                                                acc[mi][ni], 0, 0, 0);
    }
  }
#undef STAGE_AB

#pragma unroll
  for (int mi = 0; mi < 4; ++mi) {
#pragma unroll
    for (int ni = 0; ni < 4; ++ni) {
      f32x4 v = acc[mi][ni];
      int r = m0 + wr * 64 + mi * 16 + lk * 4;
      int c = n0 + wc * 64 + ni * 16 + lr;
#pragma unroll
      for (int j = 0; j < 4; ++j)
        Cf[(size_t)(r + j) * 768 + c] = v[j];
    }
  }
}

// One-shot transpose-convert: WST (Ws^T), WXT, WHT, PRJ  (out[N][K] bf16 from in[K][N] f32)
__global__ void pack_all(const float* __restrict__ Ws, const float* __restrict__ wx,
                         const float* __restrict__ wh, const float* __restrict__ pw,
                         u16* __restrict__ WST, u16* __restrict__ WXT,
                         u16* __restrict__ WHT, u16* __restrict__ PRJ) {
  int idx = blockIdx.x * 256 + threadIdx.x;
  const float* src; u16* dst; int N; int li;
  if (idx < 65536)        { src = Ws; dst = WST; N = 256; li = idx; }
  else if (idx < 262144)  { src = wx; dst = WXT; N = 768; li = idx - 65536; }
  else if (idx < 458752)  { src = wh; dst = WHT; N = 768; li = idx - 262144; }
  else                    { src = pw; dst = PRJ; N = 256; li = idx - 458752; }
  int n = li >> 8, k = li & 255;
  dst[li] = f2bf(src[(size_t)k * N + n]);
}

// Fragment-major packing of [Wg | Ws] in 32-col strips, EVEN/ODD within strip:
// chunk c: l=c&63, ni=(c>>6)&1, kc=(c>>7)&7, s=c>>10; col n = s*32 + 2*(l&15) + ni.
__global__ void pack_bp(const float* __restrict__ Wg, const float* __restrict__ Ws,
                        u16* __restrict__ BP) {
  int c = blockIdx.x * 256 + threadIdx.x;  // 16384 chunks
  int l = c & 63, ni = (c >> 6) & 1, kc = (c >> 7) & 7, s = c >> 10;
  int n = s * 32 + ((l & 15) << 1) + ni;
  int k0 = kc * 32 + (l >> 4) * 8;
  const float* W = (n < 256) ? Wg : Ws;
  int nn = n & 255;
  u16x8 o;
#pragma unroll
  for (int e = 0; e < 8; ++e) o[e] = f2bf(W[(size_t)(k0 + e) * 256 + nn]);
  *(u16x8*)(BP + (size_t)c * 8) = o;
}

// WGAD[d][h] = sum_j Wg[d][h*32+j]*adst[h*32+j];  WGAS likewise with asrc.
__global__ void wgad_kernel(const float* __restrict__ Wg, const float* __restrict__ adst,
                            const float* __restrict__ asrc,
                            float* __restrict__ WGAD, float* __restrict__ WGAS) {
  const int h = blockIdx.x, d = threadIdx.x;
  float sd = 0.f, ss = 0.f;
#pragma unroll
  for (int j = 0; j < 32; ++j) {
    float wv = Wg[(size_t)d * 256 + h * 32 + j];
    sd += wv * adst[h * 32 + j];
    ss += wv * asrc[h * 32 + j];
  }
  WGAD[(size_t)d * 8 + h] = sd;
  WGAS[(size_t)d * 8 + h] = ss;
}

// B-fragment pack of WGAS for the E-phase MFMA (heads at cols 0-7; cols 8-15 zero).
__global__ void pack_ep(const float* __restrict__ WGAS, u16* __restrict__ EP) {
  int c = blockIdx.x * 256 + threadIdx.x;  // 512 chunks
  if (c >= 512) return;
  int l = c & 63, kc = c >> 6;
  int hh = l & 15, k0 = kc * 32 + (l >> 4) * 8;
  u16x8 o;
#pragma unroll
  for (int e = 0; e < 8; ++e)
    o[e] = (hh < 8) ? f2bf(WGAS[(size_t)(k0 + e) * 8 + hh]) : (u16)0;
  *(u16x8*)(EP + (size_t)c * 8) = o;
}

// x0 bf16 + virtual sum -> state f32/bf16 + ED (state . WGAD per head)
__global__ __launch_bounds__(256)
void prep_x_kernel(const float* __restrict__ nf, u16* __restrict__ X0,
                   float* __restrict__ state, u16* __restrict__ GS,
                   const float* __restrict__ WGAD, float* __restrict__ ED) {
  __shared__ f32x4 part[4][64];
  __shared__ float stt[256];
  __shared__ float red[4][8];
  const int b = blockIdx.x, t = threadIdx.x;
  const int c4 = t & 63, sg = t >> 6, l = t & 63;
  const f32x4* src = (const f32x4*)(nf + (size_t)b * 48 * 256);
  f32x4 acc = (f32x4){0.f, 0.f, 0.f, 0.f};
  for (int s = sg * 12; s < sg * 12 + 12; ++s) {
    f32x4 v = src[(size_t)s * 64 + c4];
    acc += v;
    u16x4 o = {f2bf(v[0]), f2bf(v[1]), f2bf(v[2]), f2bf(v[3])};
    *(u16x4*)(X0 + ((size_t)b * 48 + s) * 256 + c4 * 4) = o;
  }
  part[sg][c4] = acc;
  __syncthreads();
  if (t < 64) {
    f32x4 r = part[0][t] + part[1][t] + part[2][t] + part[3][t];
#pragma unroll
    for (int j = 0; j < 4; ++j) {
      int d = t * 4 + j;
      stt[d] = r[j];
      state[(size_t)b * 256 + d] = r[j];
      GS[(size_t)b * 512 + 256 + d] = f2bf(r[j]);
    }
  }
  __syncthreads();
  const float st = stt[t];
  float pr[8];
#pragma unroll
  for (int h = 0; h < 8; ++h) pr[h] = redsum_wave(st * WGAD[(size_t)t * 8 + h]);
  if (l == 0) {
#pragma unroll
    for (int h = 0; h < 8; ++h) red[sg][h] = pr[h];
  }
  __syncthreads();
  if (t < 8) ED[(size_t)b * 8 + t] = red[0][t] + red[1][t] + red[2][t] + red[3][t];
}

// GRU elementwise + ED for next step
__global__ void gru_kernel(const float* __restrict__ G1, const float* __restrict__ G2,
                           const float* __restrict__ bx, const float* __restrict__ bh,
                           float* __restrict__ state, u16* __restrict__ GS,
                           const float* __restrict__ WGAD, float* __restrict__ ED) {
  __shared__ float red[4][8];
  const int b = blockIdx.x, d = threadIdx.x;
  const int wv = d >> 6, l = d & 63;
  const float* g1 = G1 + (size_t)b * 768;
  const float* g2 = G2 + (size_t)b * 768;
  float xz = g1[d] + bx[d], xr = g1[256 + d] + bx[256 + d], xh = g1[512 + d] + bx[512 + d];
  float hz = g2[d] + bh[d], hr = g2[256 + d] + bh[256 + d], hh2 = g2[512 + d] + bh[512 + d];
  float z = 1.f / (1.f + expf(-(xz + hz)));
  float r = 1.f / (1.f + expf(-(xr + hr)));
  float n = tanhf(xh + r * hh2);
  float h0 = state[b * 256 + d];
  float sn = z * h0 + (1.f - z) * n;
  state[b * 256 + d] = sn;
  GS[(size_t)b * 512 + 256 + d] = f2bf(sn);
  float pr[8];
#pragma unroll
  for (int h = 0; h < 8; ++h) pr[h] = redsum_wave(sn * WGAD[(size_t)d * 8 + h]);
  if (l == 0) {
#pragma unroll
    for (int h = 0; h < 8; ++h) red[wv][h] = pr[h];
  }
  __syncthreads();
  if (d < 8) ED[(size_t)b * 8 + d] = red[0][d] + red[1][d] + red[2][d] + red[3][d];
}

extern "C" void kernel_launch(void* const* d_in, const int* in_sizes, int n_in,
                              void* d_out, int out_size, void* d_ws, size_t ws_size,
                              hipStream_t stream) {
  const float* nf  = (const float*)d_in[0];
  const float* Wg  = (const float*)d_in[2];
  const float* Ws  = (const float*)d_in[3];
  const float* asr = (const float*)d_in[4];
  const float* ads = (const float*)d_in[5];
  const float* wx  = (const float*)d_in[6];
  const float* wh  = (const float*)d_in[7];
  const float* bx  = (const float*)d_in[8];
  const float* bh  = (const float*)d_in[9];
  const float* pw  = (const float*)d_in[10];
  const float* pb  = (const float*)d_in[11];
  float* out = (float*)d_out;

  char* p = (char*)d_ws;
  size_t off = 0;
  auto alloc = [&](size_t bytes) { char* r = p + off; off += (bytes + 255) & ~255ULL; return r; };
  u16* WST   = (u16*)alloc(256 * 256 * 2);
  u16* WXT   = (u16*)alloc(768 * 256 * 2);
  u16* WHT   = (u16*)alloc(768 * 256 * 2);
  u16* PRJ   = (u16*)alloc(256 * 256 * 2);
  u16* BP    = (u16*)alloc(512 * 256 * 2);            // [Wg|Ws] fragment-major strips
  u16* EP    = (u16*)alloc(512 * 8 * 2);              // WGAS fragment pack (8KB)
  float* WGAD = (float*)alloc(256 * 8 * 4);
  float* WGAS = (float*)alloc(256 * 8 * 4);
  u16* X0    = (u16*)alloc((size_t)98304 * 256 * 2);
  u16* X1    = (u16*)alloc((size_t)98304 * 256 * 2);
  float* SV   = (float*)alloc((size_t)2048 * 256 * 4);
  float* ED   = (float*)alloc((size_t)2048 * 8 * 4);
  float* G1   = (float*)alloc((size_t)2048 * 768 * 4);
  float* G2   = (float*)alloc((size_t)2048 * 768 * 4);
  u16* GS     = (u16*)alloc((size_t)2048 * 512 * 2);  // [g0 | state] bf16
  float* ST   = (float*)alloc((size_t)2048 * 256 * 4);

  pack_all<<<2048, 256, 0, stream>>>(Ws, wx, wh, pw, WST, WXT, WHT, PRJ);
  pack_bp<<<64, 256, 0, stream>>>(Wg, Ws, BP);
  wgad_kernel<<<8, 256, 0, stream>>>(Wg, ads, asr, WGAD, WGAS);
  pack_ep<<<2, 256, 0, stream>>>(WGAS, EP);
  prep_x_kernel<<<2048, 256, 0, stream>>>(nf, X0, ST, GS, WGAD, ED);

  u16* xc = X0; u16* xn = X1;
  for (int t = 0; t < 4; ++t) {
    // sv = state @ Ws   (M=2048, N=256)
    gemm_bt<0><<<dim3(16, 2), 256, 0, stream>>>(GS + 256, 512, WST, SV, 256, nullptr);
    // fused: h + E-phase attention + g0 (+ xnext for t<3)
    if (t < 3) fused_step<16><<<1024, 128, 0, stream>>>(xc, BP, EP, SV, ED, GS, xn);
    else       fused_step<8><<<1024, 128, 0, stream>>>(xc, BP, EP, SV, ED, GS, nullptr);
    // GRU gates (both in one launch)
    gemm_gates<<<dim3(16, 12), 256, 0, stream>>>(GS, WXT, WHT, G1, G2);
    // GRU elementwise + next-step e_dst
    gru_kernel<<<2048, 256, 0, stream>>>(G1, G2, bx, bh, ST, GS, WGAD, ED);
    u16* tmp = xc; xc = xn; xn = tmp;
  }
  // out = state @ proj_w + proj_b
  gemm_bt<2><<<dim3(16, 2), 256, 0, stream>>>(GS + 256, 512, PRJ, out, 256, pb);
}